// Round 1
// baseline (882.440 us; speedup 1.0000x reference)
//
#include <hip/hip_runtime.h>

typedef unsigned short u16;
typedef unsigned int u32;
typedef __attribute__((ext_vector_type(8))) short s16x8;
typedef __attribute__((ext_vector_type(4))) float f32x4;

#define MFMA_BF16(a, b, c) __builtin_amdgcn_mfma_f32_16x16x32_bf16(a, b, c, 0, 0, 0)

__device__ __forceinline__ u16 f2bf(float f) {
  union { float f; u32 u; } c; c.f = f;
  return (u16)((c.u + 0x7FFFu + ((c.u >> 16) & 1u)) >> 16);
}

__device__ __forceinline__ void gll16(const void* g, void* l) {
  __builtin_amdgcn_global_load_lds((const __attribute__((address_space(1))) void*)g,
                                   (__attribute__((address_space(3))) void*)l, 16, 0, 0);
}

__device__ __forceinline__ f32x4 f4zero() { f32x4 z = {0.f, 0.f, 0.f, 0.f}; return z; }

// ---------------- prep: f32 -> bf16 convert ----------------
__global__ void cvt_bf16_kernel(const float4* __restrict__ in, u16* __restrict__ out, int n4) {
  int i = blockIdx.x * 256 + threadIdx.x;
  if (i >= n4) return;
  float4 v = in[i];
  uint2 w;
  w.x = (u32)f2bf(v.x) | ((u32)f2bf(v.y) << 16);
  w.y = (u32)f2bf(v.z) | ((u32)f2bf(v.w) << 16);
  *reinterpret_cast<uint2*>(out + (size_t)i * 4) = w;
}

// ---------------- prep: transpose + convert (R x C f32 -> C x R bf16) ----------------
__global__ void transpose_cvt_kernel(const float* __restrict__ in, u16* __restrict__ out,
                                     int R, int C) {
  __shared__ float tile[32][33];
  int tx = threadIdx.x, ty = threadIdx.y;
  int r0 = blockIdx.y * 32, c0 = blockIdx.x * 32;
#pragma unroll
  for (int i = 0; i < 32; i += 8)
    tile[ty + i][tx] = in[(size_t)(r0 + ty + i) * C + c0 + tx];
  __syncthreads();
#pragma unroll
  for (int i = 0; i < 32; i += 8)
    out[(size_t)(c0 + ty + i) * R + r0 + tx] = f2bf(tile[tx][ty + i]);
}

// ---------------- GEMM: C[M,N] = A[M,K] * Bt[N,K]^T  (bf16 in, f32 acc) ----------------
// EPI 0: store f32 to Cf (ld = N).
// EPI 1: qkv epilogue: col<4096 -> Cq bf16 [m][col]; col<4224 -> Ck bf16 [m][col-4096];
//        else -> Cvt bf16 [b][d][s] with b=m>>11, s=m&2047, d=col-4224.
template<int EPI>
__global__ __launch_bounds__(256)
void gemm_bt_kernel(const u16* __restrict__ A, const u16* __restrict__ Bt,
                    float* __restrict__ Cf, u16* __restrict__ Cq,
                    u16* __restrict__ Ck, u16* __restrict__ Cvt,
                    int N, int K) {
  __shared__ __align__(16) u16 As[128 * 32];
  __shared__ __align__(16) u16 Bs[128 * 32];
  const int t = threadIdx.x;
  const int w = t >> 6, l = t & 63;
  const int li = l & 15, g = l >> 4;
  const int bm = blockIdx.y, bn = blockIdx.x;
  const int wm = w >> 1, wn = w & 1;

  f32x4 acc[4][4];
#pragma unroll
  for (int i = 0; i < 4; ++i)
#pragma unroll
    for (int j = 0; j < 4; ++j) acc[i][j] = f4zero();

  const u16* ga = A + (size_t)(bm * 128 + (t >> 2)) * K + (t & 3) * 8;
  const u16* gb = Bt + (size_t)(bn * 128 + (t >> 2)) * K + (t & 3) * 8;
  char* la = (char*)As + w * 1024;
  char* lb = (char*)Bs + w * 1024;
  const size_t rowskip = (size_t)64 * K;

  for (int k0 = 0; k0 < K; k0 += 32) {
    __syncthreads();
    gll16(ga, la);
    gll16(ga + rowskip, la + 4096);
    gll16(gb, lb);
    gll16(gb + rowskip, lb + 4096);
    ga += 32; gb += 32;
    __syncthreads();
    s16x8 af[4], bf[4];
#pragma unroll
    for (int mi = 0; mi < 4; ++mi)
      af[mi] = *(const s16x8*)&As[(wm * 64 + mi * 16 + li) * 32 + g * 8];
#pragma unroll
    for (int ni = 0; ni < 4; ++ni)
      bf[ni] = *(const s16x8*)&Bs[(wn * 64 + ni * 16 + li) * 32 + g * 8];
#pragma unroll
    for (int mi = 0; mi < 4; ++mi)
#pragma unroll
      for (int ni = 0; ni < 4; ++ni)
        acc[mi][ni] = MFMA_BF16(af[mi], bf[ni], acc[mi][ni]);
  }

#pragma unroll
  for (int mi = 0; mi < 4; ++mi) {
#pragma unroll
    for (int ni = 0; ni < 4; ++ni) {
      const int row0 = bm * 128 + wm * 64 + mi * 16 + g * 4;
      const int col = bn * 128 + wn * 64 + ni * 16 + li;
#pragma unroll
      for (int r = 0; r < 4; ++r) {
        const int m = row0 + r;
        const float v = acc[mi][ni][r];
        if (EPI == 0) {
          Cf[(size_t)m * N + col] = v;
        } else {
          if (col < 4096) {
            Cq[(size_t)m * 4096 + col] = f2bf(v);
          } else if (col < 4224) {
            Ck[(size_t)m * 128 + (col - 4096)] = f2bf(v);
          } else {
            Cvt[((size_t)(m >> 11) * 128 + (col - 4224)) * 2048 + (m & 2047)] = f2bf(v);
          }
        }
      }
    }
  }
}

// ---------------- flash attention (MQA), swapped-operand, 1 wave / 32 q-rows ----------------
// qbuf: (B*S, 4096) bf16 [token][h*128+d]; kbuf: (B*S, 128) bf16; vtbuf: (B,128,S) bf16
// obuf: (B*S, 4096) bf16
__global__ __launch_bounds__(64)
void attn_kernel(const u16* __restrict__ qbuf, const u16* __restrict__ kbuf,
                 const u16* __restrict__ vtbuf, u16* __restrict__ obuf) {
  const int S = 2048;
  const int qt = blockIdx.x, h = blockIdx.y, b = blockIdx.z;
  const int q0 = qt * 32;
  const int l = threadIdx.x, li = l & 15, g = l >> 4;
  const float slope = exp2f(-0.25f * (float)(h + 1));
  const float scaling = 0.08838834764831845f;   // 128^-0.5
  const float L2E = 1.4426950408889634f;

  __shared__ __align__(16) u16 Plds[32][40];

  // Q^T fragments (B-operand of S^T = K * Q^T): col q = 16*nq+li, k-dim d contiguous
  s16x8 bq[2][4];
#pragma unroll
  for (int nq = 0; nq < 2; ++nq)
#pragma unroll
    for (int kk = 0; kk < 4; ++kk)
      bq[nq][kk] = *(const s16x8*)&qbuf[(size_t)(b * S + q0 + nq * 16 + li) * 4096
                                        + h * 128 + kk * 32 + g * 8];

  f32x4 acc[8][2];   // O^T: d-frags x q-frags; lane col = q (= li+16*nq), rows = d
#pragma unroll
  for (int mf = 0; mf < 8; ++mf) { acc[mf][0] = f4zero(); acc[mf][1] = f4zero(); }
  float m_[2] = {-1e30f, -1e30f};
  float l_[2] = {0.f, 0.f};

  for (int tt = 0; tt <= qt; ++tt) {
    const int k0 = tt * 32;
    f32x4 sc[2][2];
    sc[0][0] = f4zero(); sc[0][1] = f4zero(); sc[1][0] = f4zero(); sc[1][1] = f4zero();
    // S^T[kpos][q] += K[kpos][d] * Q^T[d][q]
#pragma unroll
    for (int kk = 0; kk < 4; ++kk)
#pragma unroll
      for (int mk = 0; mk < 2; ++mk) {
        s16x8 ak = *(const s16x8*)&kbuf[(size_t)(b * S + k0 + mk * 16 + li) * 128
                                        + kk * 32 + g * 8];
        sc[mk][0] = MFMA_BF16(ak, bq[0][kk], sc[mk][0]);
        sc[mk][1] = MFMA_BF16(ak, bq[1][kk], sc[mk][1]);
      }

    // online softmax over kpos (rows of S^T): stats are per-lane (col = q)
#pragma unroll
    for (int nq = 0; nq < 2; ++nq) {
      const int qi = q0 + nq * 16 + li;
      float sv[2][4];
      float mx = m_[nq];
#pragma unroll
      for (int mk = 0; mk < 2; ++mk)
#pragma unroll
        for (int r = 0; r < 4; ++r) {
          const int kp = k0 + mk * 16 + g * 4 + r;
          float s = sc[mk][nq][r] * scaling + slope * (float)(kp - qi);
          s = (kp <= qi) ? s : -1e30f;
          sv[mk][r] = s;
          mx = fmaxf(mx, s);
        }
      mx = fmaxf(mx, __shfl_xor(mx, 16));
      mx = fmaxf(mx, __shfl_xor(mx, 32));
      const float scale = exp2f((m_[nq] - mx) * L2E);
      m_[nq] = mx;
      l_[nq] *= scale;
#pragma unroll
      for (int mf = 0; mf < 8; ++mf) acc[mf][nq] *= scale;
      float sum = 0.f;
#pragma unroll
      for (int mk = 0; mk < 2; ++mk) {
        float e0 = exp2f((sv[mk][0] - mx) * L2E);
        float e1 = exp2f((sv[mk][1] - mx) * L2E);
        float e2 = exp2f((sv[mk][2] - mx) * L2E);
        float e3 = exp2f((sv[mk][3] - mx) * L2E);
        sum += e0 + e1 + e2 + e3;
        uint2 wv;
        wv.x = (u32)f2bf(e0) | ((u32)f2bf(e1) << 16);
        wv.y = (u32)f2bf(e2) | ((u32)f2bf(e3) << 16);
        // P[q][kpos], 4 consecutive kpos per lane -> 8B write
        *reinterpret_cast<uint2*>(&Plds[nq * 16 + li][mk * 16 + g * 4]) = wv;
      }
      sum += __shfl_xor(sum, 16);
      sum += __shfl_xor(sum, 32);
      l_[nq] += sum;
    }
    __syncthreads();
    // O^T[d][q] += V^T[d][kpos] * P^T[kpos][q]
    s16x8 pb0 = *(const s16x8*)&Plds[li][g * 8];
    s16x8 pb1 = *(const s16x8*)&Plds[16 + li][g * 8];
#pragma unroll
    for (int mf = 0; mf < 8; ++mf) {
      s16x8 av = *(const s16x8*)&vtbuf[((size_t)b * 128 + mf * 16 + li) * 2048 + k0 + g * 8];
      acc[mf][0] = MFMA_BF16(av, pb0, acc[mf][0]);
      acc[mf][1] = MFMA_BF16(av, pb1, acc[mf][1]);
    }
    __syncthreads();
  }

#pragma unroll
  for (int nq = 0; nq < 2; ++nq) {
    const float inv = 1.f / l_[nq];
    const size_t rowbase = (size_t)(b * S + q0 + nq * 16 + li) * 4096 + h * 128;
#pragma unroll
    for (int mf = 0; mf < 8; ++mf) {
      f32x4 v = acc[mf][nq];
      uint2 wv;
      wv.x = (u32)f2bf(v[0] * inv) | ((u32)f2bf(v[1] * inv) << 16);
      wv.y = (u32)f2bf(v[2] * inv) | ((u32)f2bf(v[3] * inv) << 16);
      *reinterpret_cast<uint2*>(&obuf[rowbase + mf * 16 + g * 4]) = wv;
    }
  }
}

// ---------------- launch ----------------
extern "C" void kernel_launch(void* const* d_in, const int* in_sizes, int n_in,
                              void* d_out, int out_size, void* d_ws, size_t ws_size,
                              hipStream_t stream) {
  (void)in_sizes; (void)n_in; (void)out_size; (void)ws_size;
  const float* hidden = (const float*)d_in[0];
  const float* w_qkv = (const float*)d_in[1];
  const float* w_c = (const float*)d_in[2];
  float* out = (float*)d_out;
  char* ws = (char*)d_ws;

  // workspace layout (100 MB total)
  u16* hid_bf = (u16*)(ws + 0);            // 32 MB  (B*S,4096) bf16; reused as attn out
  u16* wT     = (u16*)(ws + 33554432);     // 34 MB  w_qkv^T then w_c^T (N,K) bf16
  u16* qbuf   = (u16*)(ws + 69206016);     // 32 MB  (B*S,4096) bf16
  u16* kbuf   = (u16*)(ws + 102760448);    // 1 MB   (B*S,128) bf16
  u16* vtbuf  = (u16*)(ws + 103809024);    // 1 MB   (B,128,S) bf16

  cvt_bf16_kernel<<<16384, 256, 0, stream>>>((const float4*)hidden, hid_bf, 4194304);
  transpose_cvt_kernel<<<dim3(136, 128), dim3(32, 8), 0, stream>>>(w_qkv, wT, 4096, 4352);
  gemm_bt_kernel<1><<<dim3(34, 32), 256, 0, stream>>>(hid_bf, wT, nullptr, qbuf, kbuf, vtbuf,
                                                      4352, 4096);
  attn_kernel<<<dim3(64, 32, 2), 64, 0, stream>>>(qbuf, kbuf, vtbuf, hid_bf);
  transpose_cvt_kernel<<<dim3(128, 128), dim3(32, 8), 0, stream>>>(w_c, wT, 4096, 4096);
  gemm_bt_kernel<0><<<dim3(32, 32), 256, 0, stream>>>(hid_bf, wT, out, nullptr, nullptr, nullptr,
                                                      4096, 4096);
}

// Round 2
// 845.865 us; speedup vs baseline: 1.0432x; 1.0432x over previous
//
#include <hip/hip_runtime.h>
#include <hip/hip_bf16.h>

typedef unsigned short u16;
typedef unsigned int u32;
typedef __attribute__((ext_vector_type(8))) short s16x8;
typedef __attribute__((ext_vector_type(4))) float f32x4;

#define MFMA_BF16(a, b, c) __builtin_amdgcn_mfma_f32_16x16x32_bf16(a, b, c, 0, 0, 0)

__device__ __forceinline__ u16 f2bf(float f) {
  union { float f; u32 u; } c; c.f = f;
  return (u16)((c.u + 0x7FFFu + ((c.u >> 16) & 1u)) >> 16);
}

__device__ __forceinline__ u32 pkbf(float a, float b) {
  float2 t; t.x = a; t.y = b;
  __hip_bfloat162 h = __float22bfloat162_rn(t);
  union { __hip_bfloat162 h; u32 u; } c; c.h = h; return c.u;
}

__device__ __forceinline__ void gll16(const void* g, void* l) {
  __builtin_amdgcn_global_load_lds((const __attribute__((address_space(1))) void*)g,
                                   (__attribute__((address_space(3))) void*)l, 16, 0, 0);
}

__device__ __forceinline__ f32x4 f4zero() { f32x4 z = {0.f, 0.f, 0.f, 0.f}; return z; }

// ---------------- prep: f32 -> bf16 convert ----------------
__global__ void cvt_bf16_kernel(const float4* __restrict__ in, u16* __restrict__ out, int n4) {
  int i = blockIdx.x * 256 + threadIdx.x;
  if (i >= n4) return;
  float4 v = in[i];
  uint2 w;
  w.x = (u32)f2bf(v.x) | ((u32)f2bf(v.y) << 16);
  w.y = (u32)f2bf(v.z) | ((u32)f2bf(v.w) << 16);
  *reinterpret_cast<uint2*>(out + (size_t)i * 4) = w;
}

// ---------------- prep: transpose + convert (R x C f32 -> C x R bf16) ----------------
__global__ void transpose_cvt_kernel(const float* __restrict__ in, u16* __restrict__ out,
                                     int R, int C) {
  __shared__ float tile[32][33];
  int tx = threadIdx.x, ty = threadIdx.y;
  int r0 = blockIdx.y * 32, c0 = blockIdx.x * 32;
#pragma unroll
  for (int i = 0; i < 32; i += 8)
    tile[ty + i][tx] = in[(size_t)(r0 + ty + i) * C + c0 + tx];
  __syncthreads();
#pragma unroll
  for (int i = 0; i < 32; i += 8)
    out[(size_t)(c0 + ty + i) * R + r0 + tx] = f2bf(tile[tx][ty + i]);
}

// ---------------- GEMM: C[M,N] = A[M,K] * Bt[N,K]^T  (bf16 in, f32 acc) ----------------
// EPI 0: store f32 to Cf (ld = N).
// EPI 1: qkv epilogue: col<4096 -> Cq bf16 [m][col]; col<4224 -> Ck bf16 [m][col-4096];
//        else -> Cvt bf16 tiled (b, s>>5, d, s&31) with b=m>>11, s=m&2047, d=col-4224.
template<int EPI>
__global__ __launch_bounds__(256)
void gemm_bt_kernel(const u16* __restrict__ A, const u16* __restrict__ Bt,
                    float* __restrict__ Cf, u16* __restrict__ Cq,
                    u16* __restrict__ Ck, u16* __restrict__ Cvt,
                    int N, int K) {
  __shared__ __align__(16) u16 As[128 * 32];
  __shared__ __align__(16) u16 Bs[128 * 32];
  const int t = threadIdx.x;
  const int w = t >> 6, l = t & 63;
  const int li = l & 15, g = l >> 4;
  const int bm = blockIdx.y, bn = blockIdx.x;
  const int wm = w >> 1, wn = w & 1;

  f32x4 acc[4][4];
#pragma unroll
  for (int i = 0; i < 4; ++i)
#pragma unroll
    for (int j = 0; j < 4; ++j) acc[i][j] = f4zero();

  const u16* ga = A + (size_t)(bm * 128 + (t >> 2)) * K + (t & 3) * 8;
  const u16* gb = Bt + (size_t)(bn * 128 + (t >> 2)) * K + (t & 3) * 8;
  char* la = (char*)As + w * 1024;
  char* lb = (char*)Bs + w * 1024;
  const size_t rowskip = (size_t)64 * K;

  for (int k0 = 0; k0 < K; k0 += 32) {
    __syncthreads();
    gll16(ga, la);
    gll16(ga + rowskip, la + 4096);
    gll16(gb, lb);
    gll16(gb + rowskip, lb + 4096);
    ga += 32; gb += 32;
    __syncthreads();
    s16x8 af[4], bf[4];
#pragma unroll
    for (int mi = 0; mi < 4; ++mi)
      af[mi] = *(const s16x8*)&As[(wm * 64 + mi * 16 + li) * 32 + g * 8];
#pragma unroll
    for (int ni = 0; ni < 4; ++ni)
      bf[ni] = *(const s16x8*)&Bs[(wn * 64 + ni * 16 + li) * 32 + g * 8];
#pragma unroll
    for (int mi = 0; mi < 4; ++mi)
#pragma unroll
      for (int ni = 0; ni < 4; ++ni)
        acc[mi][ni] = MFMA_BF16(af[mi], bf[ni], acc[mi][ni]);
  }

#pragma unroll
  for (int mi = 0; mi < 4; ++mi) {
#pragma unroll
    for (int ni = 0; ni < 4; ++ni) {
      const int row0 = bm * 128 + wm * 64 + mi * 16 + g * 4;
      const int col = bn * 128 + wn * 64 + ni * 16 + li;
#pragma unroll
      for (int r = 0; r < 4; ++r) {
        const int m = row0 + r;
        const float v = acc[mi][ni][r];
        if (EPI == 0) {
          Cf[(size_t)m * N + col] = v;
        } else {
          if (col < 4096) {
            Cq[(size_t)m * 4096 + col] = f2bf(v);
          } else if (col < 4224) {
            Ck[(size_t)m * 128 + (col - 4096)] = f2bf(v);
          } else {
            const int bb = m >> 11, s = m & 2047, d = col - 4224;
            Cvt[(((size_t)bb * 64 + (s >> 5)) * 128 + d) * 32 + (s & 31)] = f2bf(v);
          }
        }
      }
    }
  }
}

// ---------------- flash attention (MQA), swapped-operand, reverse-k + defer-max ----------
// 4 waves / block = 4 heads sharing the same q-tile (L1 reuse of K/V).
// qbuf: (B*S, 4096) bf16; kbuf: (B*S, 128) bf16; vt: (B, S/32, 128, 32) bf16 tiled
// obuf: (B*S, 4096) bf16
__global__ __launch_bounds__(256)
void attn_kernel(const u16* __restrict__ qbuf, const u16* __restrict__ kbuf,
                 const u16* __restrict__ vt, u16* __restrict__ obuf) {
  const int S = 2048;
  const int qt = blockIdx.x, b = blockIdx.z;
  const int w = threadIdx.x >> 6;
  const int h = blockIdx.y * 4 + w;
  const int l = threadIdx.x & 63, li = l & 15, g = l >> 4;
  const int q0 = qt * 32;

  const float L2E = 1.4426950408889634f;
  const float slope = exp2f(-0.25f * (float)(h + 1));
  const float c1 = 0.08838834764831845f * L2E;   // scaling * log2(e)
  const float sl2 = slope * L2E;                 // slope  * log2(e)

  __shared__ __align__(16) u16 P[4][32][40];     // per-wave P buffer [q][kp]
  u16 (*Pw)[40] = P[w];

  // Q^T B-frags: lane (li,g) holds Q[q0+nq*16+li][kk*32+g*8 .. +7]
  s16x8 bq[2][4];
#pragma unroll
  for (int nq = 0; nq < 2; ++nq)
#pragma unroll
    for (int kk = 0; kk < 4; ++kk)
      bq[nq][kk] = *(const s16x8*)&qbuf[(size_t)(b * S + q0 + nq * 16 + li) * 4096
                                        + h * 128 + kk * 32 + g * 8];

  f32x4 acc[8][2];
#pragma unroll
  for (int mf = 0; mf < 8; ++mf) { acc[mf][0] = f4zero(); acc[mf][1] = f4zero(); }
  float m_[2] = {-3e38f, -3e38f};
  float lp[2] = {0.f, 0.f};                       // lane-partial softmax denominator

  // per-element bias constants (log2 domain): bias(kp,qi) = bb[nq] + cjr[mk*4+r]
  float cjr[8];
#pragma unroll
  for (int j = 0; j < 8; ++j) cjr[j] = sl2 * (float)((j >> 2) * 16 + (j & 3));
  float bb[2];
#pragma unroll
  for (int nq = 0; nq < 2; ++nq)
    bb[nq] = sl2 * (float)(g * 4 - nq * 16 - li);  // at kt==qt (k0==q0)
  const float bstep = sl2 * 32.f;

  for (int kt = qt; kt >= 0; --kt) {
    const int k0 = kt * 32;
    // ---- QK: S^T[kp][q] ----
    f32x4 sc[2][2];
    sc[0][0] = f4zero(); sc[0][1] = f4zero(); sc[1][0] = f4zero(); sc[1][1] = f4zero();
#pragma unroll
    for (int kk = 0; kk < 4; ++kk)
#pragma unroll
      for (int mk = 0; mk < 2; ++mk) {
        s16x8 ak = *(const s16x8*)&kbuf[(size_t)(b * S + k0 + mk * 16 + li) * 128
                                        + kk * 32 + g * 8];
        sc[mk][0] = MFMA_BF16(ak, bq[0][kk], sc[mk][0]);
        sc[mk][1] = MFMA_BF16(ak, bq[1][kk], sc[mk][1]);
      }

    // ---- softmax (log2 domain), per-lane stats (col = q) ----
#pragma unroll
    for (int nq = 0; nq < 2; ++nq) {
      float sv[8];
      float pm = -3e38f;
      if (kt == qt) {  // diagonal tile: causal mask + exact init of m_
#pragma unroll
        for (int mk = 0; mk < 2; ++mk)
#pragma unroll
          for (int r = 0; r < 4; ++r) {
            const int kd = mk * 16 + g * 4 + r - (nq * 16 + li);
            float s = fmaf(sc[mk][nq][r], c1, bb[nq] + cjr[mk * 4 + r]);
            s = (kd <= 0) ? s : -1e30f;
            sv[mk * 4 + r] = s;
            pm = fmaxf(pm, s);
          }
        pm = fmaxf(pm, __shfl_xor(pm, 16));
        pm = fmaxf(pm, __shfl_xor(pm, 32));
        m_[nq] = pm;
      } else {         // off-diagonal: no mask; defer-max
#pragma unroll
        for (int mk = 0; mk < 2; ++mk)
#pragma unroll
          for (int r = 0; r < 4; ++r) {
            float s = fmaf(sc[mk][nq][r], c1, bb[nq] + cjr[mk * 4 + r]);
            sv[mk * 4 + r] = s;
            pm = fmaxf(pm, s);
          }
        if (__any(pm > m_[nq])) {   // rare: running max grew going backwards
          pm = fmaxf(pm, __shfl_xor(pm, 16));
          pm = fmaxf(pm, __shfl_xor(pm, 32));
          const float nm = fmaxf(m_[nq], pm);
          const float scale = exp2f(m_[nq] - nm);
#pragma unroll
          for (int mf = 0; mf < 8; ++mf) acc[mf][nq] *= scale;
          lp[nq] *= scale;
          m_[nq] = nm;
        }
      }
      const float mref = m_[nq];
      float e[8];
#pragma unroll
      for (int j = 0; j < 8; ++j) e[j] = exp2f(sv[j] - mref);
      lp[nq] += ((e[0] + e[1]) + (e[2] + e[3])) + ((e[4] + e[5]) + (e[6] + e[7]));
#pragma unroll
      for (int mk = 0; mk < 2; ++mk) {
        uint2 wv;
        wv.x = pkbf(e[mk * 4 + 0], e[mk * 4 + 1]);
        wv.y = pkbf(e[mk * 4 + 2], e[mk * 4 + 3]);
        *reinterpret_cast<uint2*>(&Pw[nq * 16 + li][mk * 16 + g * 4]) = wv;
      }
      bb[nq] -= bstep;
    }

    // ---- PV: O^T[d][q] += V^T[d][kp] * P^T[kp][q] ----
    // Pw is per-wave: same-wave ds_write->ds_read ordering handled by compiler waitcnt.
    s16x8 pb0 = *(const s16x8*)&Pw[li][g * 8];
    s16x8 pb1 = *(const s16x8*)&Pw[16 + li][g * 8];
    const u16* vbase = &vt[(((size_t)b * 64 + kt) * 128) * 32];
#pragma unroll
    for (int mf = 0; mf < 8; ++mf) {
      s16x8 av = *(const s16x8*)&vbase[(mf * 16 + li) * 32 + g * 8];
      acc[mf][0] = MFMA_BF16(av, pb0, acc[mf][0]);
      acc[mf][1] = MFMA_BF16(av, pb1, acc[mf][1]);
    }
  }

#pragma unroll
  for (int nq = 0; nq < 2; ++nq) {
    float ls = lp[nq];
    ls += __shfl_xor(ls, 16);
    ls += __shfl_xor(ls, 32);
    const float inv = 1.f / ls;
    const size_t rowbase = (size_t)(b * S + q0 + nq * 16 + li) * 4096 + h * 128;
#pragma unroll
    for (int mf = 0; mf < 8; ++mf) {
      f32x4 v = acc[mf][nq];
      uint2 wv;
      wv.x = pkbf(v[0] * inv, v[1] * inv);
      wv.y = pkbf(v[2] * inv, v[3] * inv);
      *reinterpret_cast<uint2*>(&obuf[rowbase + mf * 16 + g * 4]) = wv;
    }
  }
}

// ---------------- launch ----------------
extern "C" void kernel_launch(void* const* d_in, const int* in_sizes, int n_in,
                              void* d_out, int out_size, void* d_ws, size_t ws_size,
                              hipStream_t stream) {
  (void)in_sizes; (void)n_in; (void)out_size; (void)ws_size;
  const float* hidden = (const float*)d_in[0];
  const float* w_qkv = (const float*)d_in[1];
  const float* w_c = (const float*)d_in[2];
  float* out = (float*)d_out;
  char* ws = (char*)d_ws;

  // workspace layout (100 MB total)
  u16* hid_bf = (u16*)(ws + 0);            // 32 MB  (B*S,4096) bf16; reused as attn out
  u16* wT     = (u16*)(ws + 33554432);     // 34 MB  w_qkv^T then w_c^T (N,K) bf16
  u16* qbuf   = (u16*)(ws + 69206016);     // 32 MB  (B*S,4096) bf16
  u16* kbuf   = (u16*)(ws + 102760448);    // 1 MB   (B*S,128) bf16
  u16* vtbuf  = (u16*)(ws + 103809024);    // 1 MB   (B, S/32, 128, 32) bf16 tiled

  cvt_bf16_kernel<<<16384, 256, 0, stream>>>((const float4*)hidden, hid_bf, 4194304);
  transpose_cvt_kernel<<<dim3(136, 128), dim3(32, 8), 0, stream>>>(w_qkv, wT, 4096, 4352);
  gemm_bt_kernel<1><<<dim3(34, 32), 256, 0, stream>>>(hid_bf, wT, nullptr, qbuf, kbuf, vtbuf,
                                                      4352, 4096);
  attn_kernel<<<dim3(64, 8, 2), 256, 0, stream>>>(qbuf, kbuf, vtbuf, hid_bf);
  transpose_cvt_kernel<<<dim3(128, 128), dim3(32, 8), 0, stream>>>(w_c, wT, 4096, 4096);
  gemm_bt_kernel<0><<<dim3(32, 32), 256, 0, stream>>>(hid_bf, wT, out, nullptr, nullptr, nullptr,
                                                      4096, 4096);
}

// Round 3
// 635.241 us; speedup vs baseline: 1.3891x; 1.3316x over previous
//
#include <hip/hip_runtime.h>
#include <hip/hip_bf16.h>

typedef unsigned short u16;
typedef unsigned int u32;
typedef __attribute__((ext_vector_type(8))) short s16x8;
typedef __attribute__((ext_vector_type(4))) float f32x4;

#define MFMA_BF16(a, b, c) __builtin_amdgcn_mfma_f32_16x16x32_bf16(a, b, c, 0, 0, 0)

__device__ __forceinline__ u16 f2bf(float f) {
  union { float f; u32 u; } c; c.f = f;
  return (u16)((c.u + 0x7FFFu + ((c.u >> 16) & 1u)) >> 16);
}

__device__ __forceinline__ u32 pkbf(float a, float b) {
  float2 t; t.x = a; t.y = b;
  __hip_bfloat162 h = __float22bfloat162_rn(t);
  union { __hip_bfloat162 h; u32 u; } c; c.h = h; return c.u;
}

__device__ __forceinline__ void gll16(const void* g, void* l) {
  __builtin_amdgcn_global_load_lds((const __attribute__((address_space(1))) void*)g,
                                   (__attribute__((address_space(3))) void*)l, 16, 0, 0);
}

__device__ __forceinline__ f32x4 f4zero() { f32x4 z = {0.f, 0.f, 0.f, 0.f}; return z; }

// ---------------- prep: f32 -> bf16 convert ----------------
__global__ void cvt_bf16_kernel(const float4* __restrict__ in, u16* __restrict__ out, int n4) {
  int i = blockIdx.x * 256 + threadIdx.x;
  if (i >= n4) return;
  float4 v = in[i];
  uint2 w;
  w.x = (u32)f2bf(v.x) | ((u32)f2bf(v.y) << 16);
  w.y = (u32)f2bf(v.z) | ((u32)f2bf(v.w) << 16);
  *reinterpret_cast<uint2*>(out + (size_t)i * 4) = w;
}

// ---------------- prep: transpose + convert (R x C f32 -> C x R bf16) ----------------
__global__ void transpose_cvt_kernel(const float* __restrict__ in, u16* __restrict__ out,
                                     int R, int C) {
  __shared__ float tile[32][33];
  int tx = threadIdx.x, ty = threadIdx.y;
  int r0 = blockIdx.y * 32, c0 = blockIdx.x * 32;
#pragma unroll
  for (int i = 0; i < 32; i += 8)
    tile[ty + i][tx] = in[(size_t)(r0 + ty + i) * C + c0 + tx];
  __syncthreads();
#pragma unroll
  for (int i = 0; i < 32; i += 8)
    out[(size_t)(c0 + ty + i) * R + r0 + tx] = f2bf(tile[tx][ty + i]);
}

// ---------------- GEMM: C[M,N] = A[M,K] * Bt[N,K]^T  (bf16 in, f32 acc) ----------------
// EPI 0: store f32 to Cf (ld = N).
// EPI 1: qkv epilogue: col<4096 -> Cq bf16 [m][col];
//        col<4224 -> K fragment-linear: frag=(mk*4+kk), off=(tb*8+frag)*512+(g*16+li)*8+e
//        else    -> V fragment-linear: frag=mf,        off=(tb*8+frag)*512+(g*16+li)*8+e
template<int EPI>
__global__ __launch_bounds__(256)
void gemm_bt_kernel(const u16* __restrict__ A, const u16* __restrict__ Bt,
                    float* __restrict__ Cf, u16* __restrict__ Cq,
                    u16* __restrict__ Ck, u16* __restrict__ Cvt,
                    int N, int K) {
  __shared__ __align__(16) u16 As[128 * 32];
  __shared__ __align__(16) u16 Bs[128 * 32];
  const int t = threadIdx.x;
  const int w = t >> 6, l = t & 63;
  const int li = l & 15, g = l >> 4;

  // XCD-aware bijective swizzle (grid counts are multiples of 8)
  const int gx = gridDim.x;
  const int nwg = gx * gridDim.y;
  int id = blockIdx.y * gx + blockIdx.x;
  id = (id & 7) * (nwg >> 3) + (id >> 3);
  const int bn = id % gx, bm = id / gx;

  const int wm = w >> 1, wn = w & 1;

  f32x4 acc[4][4];
#pragma unroll
  for (int i = 0; i < 4; ++i)
#pragma unroll
    for (int j = 0; j < 4; ++j) acc[i][j] = f4zero();

  const u16* ga = A + (size_t)(bm * 128 + (t >> 2)) * K + (t & 3) * 8;
  const u16* gb = Bt + (size_t)(bn * 128 + (t >> 2)) * K + (t & 3) * 8;
  char* la = (char*)As + w * 1024;
  char* lb = (char*)Bs + w * 1024;
  const size_t rowskip = (size_t)64 * K;

  for (int k0 = 0; k0 < K; k0 += 32) {
    __syncthreads();
    gll16(ga, la);
    gll16(ga + rowskip, la + 4096);
    gll16(gb, lb);
    gll16(gb + rowskip, lb + 4096);
    ga += 32; gb += 32;
    __syncthreads();
    s16x8 af[4], bf[4];
#pragma unroll
    for (int mi = 0; mi < 4; ++mi)
      af[mi] = *(const s16x8*)&As[(wm * 64 + mi * 16 + li) * 32 + g * 8];
#pragma unroll
    for (int ni = 0; ni < 4; ++ni)
      bf[ni] = *(const s16x8*)&Bs[(wn * 64 + ni * 16 + li) * 32 + g * 8];
#pragma unroll
    for (int mi = 0; mi < 4; ++mi)
#pragma unroll
      for (int ni = 0; ni < 4; ++ni)
        acc[mi][ni] = MFMA_BF16(af[mi], bf[ni], acc[mi][ni]);
  }

#pragma unroll
  for (int mi = 0; mi < 4; ++mi) {
#pragma unroll
    for (int ni = 0; ni < 4; ++ni) {
      const int row0 = bm * 128 + wm * 64 + mi * 16 + g * 4;
      const int col = bn * 128 + wn * 64 + ni * 16 + li;
#pragma unroll
      for (int r = 0; r < 4; ++r) {
        const int m = row0 + r;
        const float v = acc[mi][ni][r];
        if (EPI == 0) {
          Cf[(size_t)m * N + col] = v;
        } else {
          const int bb2 = m >> 11, s = m & 2047;
          const int kt = s >> 5;
          const size_t tb = (size_t)(bb2 * 64 + kt);
          if (col < 4096) {
            Cq[(size_t)m * 4096 + col] = f2bf(v);
          } else if (col < 4224) {
            const int d = col - 4096, kr = s & 31;
            const int mk = kr >> 4, lii = kr & 15;
            const int kk = d >> 5, gg = (d >> 3) & 3, e = d & 7;
            Ck[(tb * 8 + mk * 4 + kk) * 512 + (gg * 16 + lii) * 8 + e] = f2bf(v);
          } else {
            const int d = col - 4224, kp = s & 31;
            const int mf = d >> 4, lii = d & 15;
            const int gg = kp >> 3, e = kp & 7;
            Cvt[(tb * 8 + mf) * 512 + (gg * 16 + lii) * 8 + e] = f2bf(v);
          }
        }
      }
    }
  }
}

// ---------------- flash attention (MQA) ----------------
// 1 wave/block; block p handles q-tiles {63-p, p} (uniform 66 tile-units).
// K double-buffered in registers (prefetch K(kt-1) during tile kt); V issued at tile top.
// kf/vf are fragment-linear: load f of tile tb at kf[(tb*8+f)*512 + lane*8], fully coalesced.

__device__ __forceinline__ void load_ktile(s16x8 (&dst)[8], const u16* kf, size_t tb, int l) {
#pragma unroll
  for (int f = 0; f < 8; ++f)
    dst[f] = *(const s16x8*)&kf[(tb * 8 + f) * 512 + l * 8];
}

template<bool DIAG>
__device__ __forceinline__ void attn_tile(
    int kt, const u16* kf, const u16* vf, size_t bb64, int l, int li, int g,
    s16x8 (&use)[8], s16x8 (&fill)[8], bool do_fill,
    const s16x8 (&bq)[2][4], f32x4 (&acc)[8][2],
    float (&m_)[2], float (&lp)[2], float (&bias)[2],
    float c1, const float (&cjr)[8], float bstep, u16 (*Pw)[40]) {
  const size_t tb = bb64 + kt;
  s16x8 vr[8];
#pragma unroll
  for (int f = 0; f < 8; ++f)
    vr[f] = *(const s16x8*)&vf[(tb * 8 + f) * 512 + l * 8];
  if (do_fill) load_ktile(fill, kf, tb - 1, l);

  // ---- QK: S^T[kp][q] ----
  f32x4 sc[2][2];
  sc[0][0] = f4zero(); sc[0][1] = f4zero(); sc[1][0] = f4zero(); sc[1][1] = f4zero();
#pragma unroll
  for (int kk = 0; kk < 4; ++kk)
#pragma unroll
    for (int mk = 0; mk < 2; ++mk) {
      sc[mk][0] = MFMA_BF16(use[mk * 4 + kk], bq[0][kk], sc[mk][0]);
      sc[mk][1] = MFMA_BF16(use[mk * 4 + kk], bq[1][kk], sc[mk][1]);
    }

  // ---- softmax (log2 domain), per-lane stats (col = q) ----
#pragma unroll
  for (int nq = 0; nq < 2; ++nq) {
    float sv[8];
    float pm = -3e38f;
    if (DIAG) {
#pragma unroll
      for (int mk = 0; mk < 2; ++mk)
#pragma unroll
        for (int r = 0; r < 4; ++r) {
          const int kd = mk * 16 + g * 4 + r - (nq * 16 + li);
          float s = fmaf(sc[mk][nq][r], c1, bias[nq] + cjr[mk * 4 + r]);
          s = (kd <= 0) ? s : -1e30f;
          sv[mk * 4 + r] = s;
          pm = fmaxf(pm, s);
        }
      pm = fmaxf(pm, __shfl_xor(pm, 16));
      pm = fmaxf(pm, __shfl_xor(pm, 32));
      m_[nq] = pm;
    } else {
#pragma unroll
      for (int mk = 0; mk < 2; ++mk)
#pragma unroll
        for (int r = 0; r < 4; ++r) {
          float s = fmaf(sc[mk][nq][r], c1, bias[nq] + cjr[mk * 4 + r]);
          sv[mk * 4 + r] = s;
          pm = fmaxf(pm, s);
        }
      if (__any(pm > m_[nq])) {   // rare going backwards (bias decreases)
        pm = fmaxf(pm, __shfl_xor(pm, 16));
        pm = fmaxf(pm, __shfl_xor(pm, 32));
        const float nm = fmaxf(m_[nq], pm);
        const float scale = exp2f(m_[nq] - nm);
#pragma unroll
        for (int mf = 0; mf < 8; ++mf) acc[mf][nq] *= scale;
        lp[nq] *= scale;
        m_[nq] = nm;
      }
    }
    const float mref = m_[nq];
    float e[8];
#pragma unroll
    for (int j = 0; j < 8; ++j) e[j] = exp2f(sv[j] - mref);
    lp[nq] += ((e[0] + e[1]) + (e[2] + e[3])) + ((e[4] + e[5]) + (e[6] + e[7]));
#pragma unroll
    for (int mk = 0; mk < 2; ++mk) {
      uint2 wv;
      wv.x = pkbf(e[mk * 4 + 0], e[mk * 4 + 1]);
      wv.y = pkbf(e[mk * 4 + 2], e[mk * 4 + 3]);
      *reinterpret_cast<uint2*>(&Pw[nq * 16 + li][mk * 16 + g * 4]) = wv;
    }
    bias[nq] -= bstep;
  }

  // ---- PV: O^T[d][q] += V^T[d][kp] * P^T[kp][q] ----
  s16x8 pb0 = *(const s16x8*)&Pw[li][g * 8];
  s16x8 pb1 = *(const s16x8*)&Pw[16 + li][g * 8];
#pragma unroll
  for (int mf = 0; mf < 8; ++mf) {
    acc[mf][0] = MFMA_BF16(vr[mf], pb0, acc[mf][0]);
    acc[mf][1] = MFMA_BF16(vr[mf], pb1, acc[mf][1]);
  }
}

__device__ __forceinline__ void attn_qtile(
    int qt, int h, int b, const u16* qbuf, const u16* kf, const u16* vf,
    u16* obuf, int l, int li, int g, float c1, float sl2, u16 (*Pw)[40]) {
  const int S = 2048;
  const int q0 = qt * 32;
  const size_t bb64 = (size_t)b * 64;

  s16x8 bq[2][4];
#pragma unroll
  for (int nq = 0; nq < 2; ++nq)
#pragma unroll
    for (int kk = 0; kk < 4; ++kk)
      bq[nq][kk] = *(const s16x8*)&qbuf[(size_t)(b * S + q0 + nq * 16 + li) * 4096
                                        + h * 128 + kk * 32 + g * 8];

  f32x4 acc[8][2];
#pragma unroll
  for (int mf = 0; mf < 8; ++mf) { acc[mf][0] = f4zero(); acc[mf][1] = f4zero(); }
  float m_[2] = {-3e38f, -3e38f};
  float lp[2] = {0.f, 0.f};

  float cjr[8];
#pragma unroll
  for (int j = 0; j < 8; ++j) cjr[j] = sl2 * (float)((j >> 2) * 16 + (j & 3));
  float bias[2];
#pragma unroll
  for (int nq = 0; nq < 2; ++nq)
    bias[nq] = sl2 * (float)(g * 4 - nq * 16 - li);
  const float bstep = sl2 * 32.f;

  s16x8 kA[8], kB[8];
  load_ktile(kA, kf, bb64 + qt, l);
  attn_tile<true>(qt, kf, vf, bb64, l, li, g, kA, kB, qt >= 1,
                  bq, acc, m_, lp, bias, c1, cjr, bstep, Pw);
  int kt = qt - 1;
  while (kt >= 1) {
    attn_tile<false>(kt, kf, vf, bb64, l, li, g, kB, kA, true,
                     bq, acc, m_, lp, bias, c1, cjr, bstep, Pw);
    attn_tile<false>(kt - 1, kf, vf, bb64, l, li, g, kA, kB, kt >= 2,
                     bq, acc, m_, lp, bias, c1, cjr, bstep, Pw);
    kt -= 2;
  }
  if (kt == 0)
    attn_tile<false>(0, kf, vf, bb64, l, li, g, kB, kA, false,
                     bq, acc, m_, lp, bias, c1, cjr, bstep, Pw);

#pragma unroll
  for (int nq = 0; nq < 2; ++nq) {
    float ls = lp[nq];
    ls += __shfl_xor(ls, 16);
    ls += __shfl_xor(ls, 32);
    const float inv = 1.f / ls;
    const size_t rowbase = (size_t)(b * S + q0 + nq * 16 + li) * 4096 + h * 128;
#pragma unroll
    for (int mf = 0; mf < 8; ++mf) {
      f32x4 v = acc[mf][nq];
      uint2 wv;
      wv.x = pkbf(v[0] * inv, v[1] * inv);
      wv.y = pkbf(v[2] * inv, v[3] * inv);
      *reinterpret_cast<uint2*>(&obuf[rowbase + mf * 16 + g * 4]) = wv;
    }
  }
}

__global__ __launch_bounds__(64, 2)
void attn_kernel(const u16* __restrict__ qbuf, const u16* __restrict__ kf,
                 const u16* __restrict__ vf, u16* __restrict__ obuf) {
  const int p = blockIdx.x, h = blockIdx.y, b = blockIdx.z;
  const int l = threadIdx.x, li = l & 15, g = l >> 4;
  const float L2E = 1.4426950408889634f;
  const float slope = exp2f(-0.25f * (float)(h + 1));
  const float c1 = 0.08838834764831845f * L2E;
  const float sl2 = slope * L2E;
  __shared__ __align__(16) u16 P[32][40];
  attn_qtile(63 - p, h, b, qbuf, kf, vf, obuf, l, li, g, c1, sl2, P);
  attn_qtile(p, h, b, qbuf, kf, vf, obuf, l, li, g, c1, sl2, P);
}

// ---------------- launch ----------------
extern "C" void kernel_launch(void* const* d_in, const int* in_sizes, int n_in,
                              void* d_out, int out_size, void* d_ws, size_t ws_size,
                              hipStream_t stream) {
  (void)in_sizes; (void)n_in; (void)out_size; (void)ws_size;
  const float* hidden = (const float*)d_in[0];
  const float* w_qkv = (const float*)d_in[1];
  const float* w_c = (const float*)d_in[2];
  float* out = (float*)d_out;
  char* ws = (char*)d_ws;

  // workspace layout (100 MB total)
  u16* hid_bf = (u16*)(ws + 0);            // 32 MB  (B*S,4096) bf16; reused as attn out
  u16* wT     = (u16*)(ws + 33554432);     // 34 MB  w_qkv^T then w_c^T (N,K) bf16
  u16* qbuf   = (u16*)(ws + 69206016);     // 32 MB  (B*S,4096) bf16
  u16* kbuf   = (u16*)(ws + 102760448);    // 1 MB   K fragment-linear
  u16* vtbuf  = (u16*)(ws + 103809024);    // 1 MB   V fragment-linear

  cvt_bf16_kernel<<<16384, 256, 0, stream>>>((const float4*)hidden, hid_bf, 4194304);
  transpose_cvt_kernel<<<dim3(136, 128), dim3(32, 8), 0, stream>>>(w_qkv, wT, 4096, 4352);
  gemm_bt_kernel<1><<<dim3(34, 32), 256, 0, stream>>>(hid_bf, wT, nullptr, qbuf, kbuf, vtbuf,
                                                      4352, 4096);
  attn_kernel<<<dim3(32, 32, 2), 64, 0, stream>>>(qbuf, kbuf, vtbuf, hid_bf);
  transpose_cvt_kernel<<<dim3(128, 128), dim3(32, 8), 0, stream>>>(w_c, wT, 4096, 4096);
  gemm_bt_kernel<0><<<dim3(32, 32), 256, 0, stream>>>(hid_bf, wT, out, nullptr, nullptr, nullptr,
                                                      4096, 4096);
}

// Round 4
// 531.057 us; speedup vs baseline: 1.6617x; 1.1962x over previous
//
#include <hip/hip_runtime.h>
#include <hip/hip_bf16.h>

typedef unsigned short u16;
typedef unsigned int u32;
typedef __attribute__((ext_vector_type(8))) short s16x8;
typedef __attribute__((ext_vector_type(4))) float f32x4;

#define MFMA_BF16(a, b, c) __builtin_amdgcn_mfma_f32_16x16x32_bf16(a, b, c, 0, 0, 0)

__device__ __forceinline__ u16 f2bf(float f) {
  union { float f; u32 u; } c; c.f = f;
  return (u16)((c.u + 0x7FFFu + ((c.u >> 16) & 1u)) >> 16);
}

__device__ __forceinline__ u32 pkbf(float a, float b) {
  float2 t; t.x = a; t.y = b;
  __hip_bfloat162 h = __float22bfloat162_rn(t);
  union { __hip_bfloat162 h; u32 u; } c; c.h = h; return c.u;
}

__device__ __forceinline__ void gll16(const void* g, void* l) {
  __builtin_amdgcn_global_load_lds((const __attribute__((address_space(1))) void*)g,
                                   (__attribute__((address_space(3))) void*)l, 16, 0, 0);
}

__device__ __forceinline__ f32x4 f4zero() { f32x4 z = {0.f, 0.f, 0.f, 0.f}; return z; }

// ---------------- prep: f32 -> bf16 convert ----------------
__global__ void cvt_bf16_kernel(const float4* __restrict__ in, u16* __restrict__ out, int n4) {
  int i = blockIdx.x * 256 + threadIdx.x;
  if (i >= n4) return;
  float4 v = in[i];
  uint2 w;
  w.x = (u32)f2bf(v.x) | ((u32)f2bf(v.y) << 16);
  w.y = (u32)f2bf(v.z) | ((u32)f2bf(v.w) << 16);
  *reinterpret_cast<uint2*>(out + (size_t)i * 4) = w;
}

// ---------------- prep: transpose + convert (R x C f32 -> C x R bf16) ----------------
__global__ void transpose_cvt_kernel(const float* __restrict__ in, u16* __restrict__ out,
                                     int R, int C) {
  __shared__ float tile[32][33];
  int tx = threadIdx.x, ty = threadIdx.y;
  int r0 = blockIdx.y * 32, c0 = blockIdx.x * 32;
#pragma unroll
  for (int i = 0; i < 32; i += 8)
    tile[ty + i][tx] = in[(size_t)(r0 + ty + i) * C + c0 + tx];
  __syncthreads();
#pragma unroll
  for (int i = 0; i < 32; i += 8)
    out[(size_t)(c0 + ty + i) * R + r0 + tx] = f2bf(tile[tx][ty + i]);
}

// =====================================================================================
// 256x256 8-phase GEMM: C[M,N] = A[M,K] * Bt[N,K]^T  (bf16 in, f32 acc)
// 8 waves (2M x 4N), BK=64, 128 KB LDS (2 dbuf x 32 KB per operand), counted vmcnt,
// use-order LDS row permutation + 16B-granule XOR swizzle (2-way bank = free).
// EPI 0: f32 to Cf. EPI 1: q/k/v scatter (fragment-linear K and V for attention).
// =====================================================================================

// per-phase body: 12 ds_read_b128, stage (2 gll16), counted vmcnt, barrier, 16 MFMA
#define PHASE(QM, QN, PR, STAGE_STMT, WAIT_STMT) do {                                   \
  s16x8 af[4][2], bb[2][2];                                                             \
  _Pragma("unroll")                                                                     \
  for (int mi2 = 0; mi2 < 4; ++mi2) {                                                   \
    af[mi2][0] = *(const s16x8*)(smem + (PR)*32768 + (QM)*16384 + mi2*2048 + aOff0);    \
    af[mi2][1] = *(const s16x8*)(smem + (PR)*32768 + (QM)*16384 + mi2*2048 + aOff1);    \
  }                                                                                     \
  _Pragma("unroll")                                                                     \
  for (int ni2 = 0; ni2 < 2; ++ni2) {                                                   \
    bb[ni2][0] = *(const s16x8*)(smem + 65536 + (PR)*32768 + (QN)*16384 + ni2*2048 + bOff0); \
    bb[ni2][1] = *(const s16x8*)(smem + 65536 + (PR)*32768 + (QN)*16384 + ni2*2048 + bOff1); \
  }                                                                                     \
  STAGE_STMT;                                                                           \
  WAIT_STMT;                                                                            \
  __builtin_amdgcn_s_barrier();                                                         \
  asm volatile("s_waitcnt lgkmcnt(0)" ::: "memory");                                    \
  __builtin_amdgcn_s_setprio(1);                                                        \
  _Pragma("unroll")                                                                     \
  for (int ks = 0; ks < 2; ++ks)                                                        \
    _Pragma("unroll")                                                                   \
    for (int mi2 = 0; mi2 < 4; ++mi2)                                                   \
      _Pragma("unroll")                                                                 \
      for (int ni2 = 0; ni2 < 2; ++ni2)                                                 \
        acc[(QM)*4 + mi2][(QN)*2 + ni2] =                                               \
            MFMA_BF16(af[mi2][ks], bb[ni2][ks], acc[(QM)*4 + mi2][(QN)*2 + ni2]);       \
  __builtin_amdgcn_s_setprio(0);                                                        \
  __builtin_amdgcn_s_barrier();                                                         \
} while (0)

#define STAGE_PAIR(x, PW, kn) do {                                                      \
  gll16(srcA[x] + (kn), smem + (PW)*32768 + (x)*8192 + tt*16);                          \
  gll16(srcB[x] + (kn), smem + 65536 + (PW)*32768 + (x)*8192 + tt*16);                  \
} while (0)

#define VM3 asm volatile("s_waitcnt vmcnt(3)" ::: "memory")
#define VM4 asm volatile("s_waitcnt vmcnt(4)" ::: "memory")
#define VM1 asm volatile("s_waitcnt vmcnt(1)" ::: "memory")
#define VM0 asm volatile("s_waitcnt vmcnt(0)" ::: "memory")
#define NOPSTMT do {} while (0)

// steady tile: reads parity PR, stages tile (kn/64) into parity PW
#define TILE_MAIN(PR, PW, kn) do {                                                      \
  PHASE(0, 0, PR, STAGE_PAIR(0, PW, kn), VM3);                                          \
  PHASE(1, 0, PR, STAGE_PAIR(1, PW, kn), VM4);                                          \
  PHASE(0, 1, PR, STAGE_PAIR(2, PW, kn), NOPSTMT);                                      \
  PHASE(1, 1, PR, STAGE_PAIR(3, PW, kn), VM4);                                          \
} while (0)

#define TILE_LAST(PR) do {                                                              \
  PHASE(0, 0, PR, NOPSTMT, VM1);                                                        \
  PHASE(1, 0, PR, NOPSTMT, VM0);                                                        \
  PHASE(0, 1, PR, NOPSTMT, NOPSTMT);                                                    \
  PHASE(1, 1, PR, NOPSTMT, NOPSTMT);                                                    \
} while (0)

template<int EPI>
__global__ __launch_bounds__(512, 2)
void gemm256_kernel(const u16* __restrict__ A, const u16* __restrict__ Bt,
                    float* __restrict__ Cf, u16* __restrict__ Cq,
                    u16* __restrict__ Ck, u16* __restrict__ Cvt,
                    int N, int K) {
  __shared__ __align__(16) char smem[131072];
  const int tt = threadIdx.x;
  const int w = tt >> 6, l = tt & 63;
  const int li = l & 15, g = l >> 4;
  const int wm = w >> 2, wn = w & 3;

  // XCD-aware bijective swizzle (grid block-count is a multiple of 8)
  const int gx = gridDim.x;
  const int nwg = gx * gridDim.y;
  int id = blockIdx.y * gx + blockIdx.x;
  id = (id & 7) * (nwg >> 3) + (id >> 3);
  const int bn = id % gx, bm = id / gx;

  f32x4 acc[8][4];
#pragma unroll
  for (int i = 0; i < 8; ++i)
#pragma unroll
    for (int j = 0; j < 4; ++j) acc[i][j] = f4zero();

  // ---- staging source pointers (pre-permuted rows + inverse granule swizzle) ----
  // LDS A rows: rho = qm*128 + wm*64 + mi'*16 + li  -> unit x covers rho in [64x, 64x+64)
  // LDS B rows: rho = qn*128 + wn*32 + ni'*16 + li
  const int q8 = (((tt & 7) ^ ((tt >> 3) & 7)) * 8);   // granule-swizzled element col
  const u16* srcA[4];
  const u16* srcB[4];
#pragma unroll
  for (int x = 0; x < 4; ++x) {
    const int arow = (x & 1) * 128 + (x >> 1) * 64 + (tt >> 3);
    srcA[x] = A + (size_t)(bm * 256 + arow) * K + q8;
    const int rho = x * 64 + (tt >> 3);
    const int qn_ = rho >> 7, rem = rho & 127;
    const int wn_ = rem >> 5, rr = rem & 31;
    const int brow = wn_ * 64 + qn_ * 32 + rr;
    srcB[x] = Bt + (size_t)(bn * 256 + brow) * K + q8;
  }

  // ---- ds_read per-thread byte offsets (granule XOR by row&7 == li&7) ----
  const int gr0 = (g ^ (li & 7)) * 16;
  const int aOff0 = wm * 8192 + li * 128 + gr0;
  const int aOff1 = aOff0 ^ 64;
  const int bOff0 = wn * 4096 + li * 128 + gr0;
  const int bOff1 = bOff0 ^ 64;

  // ---- prologue: stage tile 0, order [A0,B0,A1,B1,A2,B2,A3,B3] ----
#pragma unroll
  for (int x = 0; x < 4; ++x) STAGE_PAIR(x, 0, 0);
  VM4;
  __builtin_amdgcn_s_barrier();

  // ---- main loop: 64 K-tiles, 2 per iteration (parity-unrolled) ----
  for (int t2 = 0; t2 < 62; t2 += 2) {
    TILE_MAIN(0, 1, (t2 + 1) * 64);
    TILE_MAIN(1, 0, (t2 + 2) * 64);
  }
  TILE_MAIN(0, 1, 63 * 64);   // tile 62, stages tile 63
  TILE_LAST(1);               // tile 63

  // ---- epilogue ----
#pragma unroll
  for (int mi = 0; mi < 8; ++mi) {
#pragma unroll
    for (int ni = 0; ni < 4; ++ni) {
      const int row0 = bm * 256 + wm * 128 + mi * 16 + g * 4;
      const int col = bn * 256 + wn * 64 + ni * 16 + li;
#pragma unroll
      for (int r = 0; r < 4; ++r) {
        const int m = row0 + r;
        const float v = acc[mi][ni][r];
        if (EPI == 0) {
          Cf[(size_t)m * N + col] = v;
        } else {
          const int bb2 = m >> 11, s = m & 2047;
          const int kt = s >> 5;
          const size_t tb = (size_t)(bb2 * 64 + kt);
          if (col < 4096) {
            Cq[(size_t)m * 4096 + col] = f2bf(v);
          } else if (col < 4224) {
            const int d = col - 4096, kr = s & 31;
            const int mk = kr >> 4, lii = kr & 15;
            const int kk = d >> 5, gg = (d >> 3) & 3, e = d & 7;
            Ck[(tb * 8 + mk * 4 + kk) * 512 + (gg * 16 + lii) * 8 + e] = f2bf(v);
          } else {
            const int d = col - 4224, kp = s & 31;
            const int mf = d >> 4, lii = d & 15;
            const int gg = kp >> 3, e = kp & 7;
            Cvt[(tb * 8 + mf) * 512 + (gg * 16 + lii) * 8 + e] = f2bf(v);
          }
        }
      }
    }
  }
}

// ---------------- flash attention (MQA) ----------------
// 1 wave/block; block p handles q-tiles {63-p, p} (uniform 66 tile-units).
// K double-buffered in registers; V issued at tile top; fragment-linear K/V loads.

__device__ __forceinline__ void load_ktile(s16x8 (&dst)[8], const u16* kf, size_t tb, int l) {
#pragma unroll
  for (int f = 0; f < 8; ++f)
    dst[f] = *(const s16x8*)&kf[(tb * 8 + f) * 512 + l * 8];
}

template<bool DIAG>
__device__ __forceinline__ void attn_tile(
    int kt, const u16* kf, const u16* vf, size_t bb64, int l, int li, int g,
    s16x8 (&use)[8], s16x8 (&fill)[8], bool do_fill,
    const s16x8 (&bq)[2][4], f32x4 (&acc)[8][2],
    float (&m_)[2], float (&lp)[2], float (&bias)[2],
    float c1, const float (&cjr)[8], float bstep, u16 (*Pw)[40]) {
  const size_t tb = bb64 + kt;
  s16x8 vr[8];
#pragma unroll
  for (int f = 0; f < 8; ++f)
    vr[f] = *(const s16x8*)&vf[(tb * 8 + f) * 512 + l * 8];
  if (do_fill) load_ktile(fill, kf, tb - 1, l);

  f32x4 sc[2][2];
  sc[0][0] = f4zero(); sc[0][1] = f4zero(); sc[1][0] = f4zero(); sc[1][1] = f4zero();
#pragma unroll
  for (int kk = 0; kk < 4; ++kk)
#pragma unroll
    for (int mk = 0; mk < 2; ++mk) {
      sc[mk][0] = MFMA_BF16(use[mk * 4 + kk], bq[0][kk], sc[mk][0]);
      sc[mk][1] = MFMA_BF16(use[mk * 4 + kk], bq[1][kk], sc[mk][1]);
    }

#pragma unroll
  for (int nq = 0; nq < 2; ++nq) {
    float sv[8];
    float pm = -3e38f;
    if (DIAG) {
#pragma unroll
      for (int mk = 0; mk < 2; ++mk)
#pragma unroll
        for (int r = 0; r < 4; ++r) {
          const int kd = mk * 16 + g * 4 + r - (nq * 16 + li);
          float s = fmaf(sc[mk][nq][r], c1, bias[nq] + cjr[mk * 4 + r]);
          s = (kd <= 0) ? s : -1e30f;
          sv[mk * 4 + r] = s;
          pm = fmaxf(pm, s);
        }
      pm = fmaxf(pm, __shfl_xor(pm, 16));
      pm = fmaxf(pm, __shfl_xor(pm, 32));
      m_[nq] = pm;
    } else {
#pragma unroll
      for (int mk = 0; mk < 2; ++mk)
#pragma unroll
        for (int r = 0; r < 4; ++r) {
          float s = fmaf(sc[mk][nq][r], c1, bias[nq] + cjr[mk * 4 + r]);
          sv[mk * 4 + r] = s;
          pm = fmaxf(pm, s);
        }
      if (__any(pm > m_[nq])) {
        pm = fmaxf(pm, __shfl_xor(pm, 16));
        pm = fmaxf(pm, __shfl_xor(pm, 32));
        const float nm = fmaxf(m_[nq], pm);
        const float scale = exp2f(m_[nq] - nm);
#pragma unroll
        for (int mf = 0; mf < 8; ++mf) acc[mf][nq] *= scale;
        lp[nq] *= scale;
        m_[nq] = nm;
      }
    }
    const float mref = m_[nq];
    float e[8];
#pragma unroll
    for (int j = 0; j < 8; ++j) e[j] = exp2f(sv[j] - mref);
    lp[nq] += ((e[0] + e[1]) + (e[2] + e[3])) + ((e[4] + e[5]) + (e[6] + e[7]));
#pragma unroll
    for (int mk = 0; mk < 2; ++mk) {
      uint2 wv;
      wv.x = pkbf(e[mk * 4 + 0], e[mk * 4 + 1]);
      wv.y = pkbf(e[mk * 4 + 2], e[mk * 4 + 3]);
      *reinterpret_cast<uint2*>(&Pw[nq * 16 + li][mk * 16 + g * 4]) = wv;
    }
    bias[nq] -= bstep;
  }

  s16x8 pb0 = *(const s16x8*)&Pw[li][g * 8];
  s16x8 pb1 = *(const s16x8*)&Pw[16 + li][g * 8];
#pragma unroll
  for (int mf = 0; mf < 8; ++mf) {
    acc[mf][0] = MFMA_BF16(vr[mf], pb0, acc[mf][0]);
    acc[mf][1] = MFMA_BF16(vr[mf], pb1, acc[mf][1]);
  }
}

__device__ __forceinline__ void attn_qtile(
    int qt, int h, int b, const u16* qbuf, const u16* kf, const u16* vf,
    u16* obuf, int l, int li, int g, float c1, float sl2, u16 (*Pw)[40]) {
  const int S = 2048;
  const int q0 = qt * 32;
  const size_t bb64 = (size_t)b * 64;

  s16x8 bq[2][4];
#pragma unroll
  for (int nq = 0; nq < 2; ++nq)
#pragma unroll
    for (int kk = 0; kk < 4; ++kk)
      bq[nq][kk] = *(const s16x8*)&qbuf[(size_t)(b * S + q0 + nq * 16 + li) * 4096
                                        + h * 128 + kk * 32 + g * 8];

  f32x4 acc[8][2];
#pragma unroll
  for (int mf = 0; mf < 8; ++mf) { acc[mf][0] = f4zero(); acc[mf][1] = f4zero(); }
  float m_[2] = {-3e38f, -3e38f};
  float lp[2] = {0.f, 0.f};

  float cjr[8];
#pragma unroll
  for (int j = 0; j < 8; ++j) cjr[j] = sl2 * (float)((j >> 2) * 16 + (j & 3));
  float bias[2];
#pragma unroll
  for (int nq = 0; nq < 2; ++nq)
    bias[nq] = sl2 * (float)(g * 4 - nq * 16 - li);
  const float bstep = sl2 * 32.f;

  s16x8 kA[8], kB[8];
  load_ktile(kA, kf, bb64 + qt, l);
  attn_tile<true>(qt, kf, vf, bb64, l, li, g, kA, kB, qt >= 1,
                  bq, acc, m_, lp, bias, c1, cjr, bstep, Pw);
  int kt = qt - 1;
  while (kt >= 1) {
    attn_tile<false>(kt, kf, vf, bb64, l, li, g, kB, kA, true,
                     bq, acc, m_, lp, bias, c1, cjr, bstep, Pw);
    attn_tile<false>(kt - 1, kf, vf, bb64, l, li, g, kA, kB, kt >= 2,
                     bq, acc, m_, lp, bias, c1, cjr, bstep, Pw);
    kt -= 2;
  }
  if (kt == 0)
    attn_tile<false>(0, kf, vf, bb64, l, li, g, kB, kA, false,
                     bq, acc, m_, lp, bias, c1, cjr, bstep, Pw);

#pragma unroll
  for (int nq = 0; nq < 2; ++nq) {
    float ls = lp[nq];
    ls += __shfl_xor(ls, 16);
    ls += __shfl_xor(ls, 32);
    const float inv = 1.f / ls;
    const size_t rowbase = (size_t)(b * S + q0 + nq * 16 + li) * 4096 + h * 128;
#pragma unroll
    for (int mf = 0; mf < 8; ++mf) {
      f32x4 v = acc[mf][nq];
      uint2 wv;
      wv.x = pkbf(v[0] * inv, v[1] * inv);
      wv.y = pkbf(v[2] * inv, v[3] * inv);
      *reinterpret_cast<uint2*>(&obuf[rowbase + mf * 16 + g * 4]) = wv;
    }
  }
}

__global__ __launch_bounds__(64, 2)
void attn_kernel(const u16* __restrict__ qbuf, const u16* __restrict__ kf,
                 const u16* __restrict__ vf, u16* __restrict__ obuf) {
  const int p = blockIdx.x, h = blockIdx.y, b = blockIdx.z;
  const int l = threadIdx.x, li = l & 15, g = l >> 4;
  const float L2E = 1.4426950408889634f;
  const float slope = exp2f(-0.25f * (float)(h + 1));
  const float c1 = 0.08838834764831845f * L2E;
  const float sl2 = slope * L2E;
  __shared__ __align__(16) u16 P[32][40];
  attn_qtile(63 - p, h, b, qbuf, kf, vf, obuf, l, li, g, c1, sl2, P);
  attn_qtile(p, h, b, qbuf, kf, vf, obuf, l, li, g, c1, sl2, P);
}

// ---------------- launch ----------------
extern "C" void kernel_launch(void* const* d_in, const int* in_sizes, int n_in,
                              void* d_out, int out_size, void* d_ws, size_t ws_size,
                              hipStream_t stream) {
  (void)in_sizes; (void)n_in; (void)out_size; (void)ws_size;
  const float* hidden = (const float*)d_in[0];
  const float* w_qkv = (const float*)d_in[1];
  const float* w_c = (const float*)d_in[2];
  float* out = (float*)d_out;
  char* ws = (char*)d_ws;

  // workspace layout (100 MB total)
  u16* hid_bf = (u16*)(ws + 0);            // 32 MB  (B*S,4096) bf16; reused as attn out
  u16* wT     = (u16*)(ws + 33554432);     // 34 MB  w_qkv^T then w_c^T (N,K) bf16
  u16* qbuf   = (u16*)(ws + 69206016);     // 32 MB  (B*S,4096) bf16
  u16* kbuf   = (u16*)(ws + 102760448);    // 1 MB   K fragment-linear
  u16* vtbuf  = (u16*)(ws + 103809024);    // 1 MB   V fragment-linear

  cvt_bf16_kernel<<<16384, 256, 0, stream>>>((const float4*)hidden, hid_bf, 4194304);
  transpose_cvt_kernel<<<dim3(136, 128), dim3(32, 8), 0, stream>>>(w_qkv, wT, 4096, 4352);
  gemm256_kernel<1><<<dim3(17, 16), 512, 0, stream>>>(hid_bf, wT, nullptr, qbuf, kbuf, vtbuf,
                                                      4352, 4096);
  attn_kernel<<<dim3(32, 32, 2), 64, 0, stream>>>(qbuf, kbuf, vtbuf, hid_bf);
  transpose_cvt_kernel<<<dim3(128, 128), dim3(32, 8), 0, stream>>>(w_c, wT, 4096, 4096);
  gemm256_kernel<0><<<dim3(16, 16), 512, 0, stream>>>(hid_bf, wT, out, nullptr, nullptr, nullptr,
                                                      4096, 4096);
}

// Round 6
// 503.885 us; speedup vs baseline: 1.7513x; 1.0539x over previous
//
#include <hip/hip_runtime.h>
#include <hip/hip_bf16.h>

typedef unsigned short u16;
typedef unsigned int u32;
typedef __attribute__((ext_vector_type(8))) short s16x8;
typedef __attribute__((ext_vector_type(4))) float f32x4;

#define MFMA_BF16(a, b, c) __builtin_amdgcn_mfma_f32_16x16x32_bf16(a, b, c, 0, 0, 0)

__device__ __forceinline__ u16 f2bf(float f) {
  union { float f; u32 u; } c; c.f = f;
  return (u16)((c.u + 0x7FFFu + ((c.u >> 16) & 1u)) >> 16);
}

__device__ __forceinline__ u32 pkbf(float a, float b) {
  float2 t; t.x = a; t.y = b;
  __hip_bfloat162 h = __float22bfloat162_rn(t);
  union { __hip_bfloat162 h; u32 u; } c; c.h = h; return c.u;
}

__device__ __forceinline__ void gll16(const void* g, void* l) {
  __builtin_amdgcn_global_load_lds((const __attribute__((address_space(1))) void*)g,
                                   (__attribute__((address_space(3))) void*)l, 16, 0, 0);
}

__device__ __forceinline__ f32x4 f4zero() { f32x4 z = {0.f, 0.f, 0.f, 0.f}; return z; }

// ---------------- prep: f32 -> bf16 convert ----------------
__global__ void cvt_bf16_kernel(const float4* __restrict__ in, u16* __restrict__ out, int n4) {
  int i = blockIdx.x * 256 + threadIdx.x;
  if (i >= n4) return;
  float4 v = in[i];
  uint2 w;
  w.x = (u32)f2bf(v.x) | ((u32)f2bf(v.y) << 16);
  w.y = (u32)f2bf(v.z) | ((u32)f2bf(v.w) << 16);
  *reinterpret_cast<uint2*>(out + (size_t)i * 4) = w;
}

// ---------------- prep: transpose + convert (R x C f32 -> C x R bf16) ----------------
__global__ void transpose_cvt_kernel(const float* __restrict__ in, u16* __restrict__ out,
                                     int R, int C) {
  __shared__ float tile[32][33];
  int tx = threadIdx.x, ty = threadIdx.y;
  int r0 = blockIdx.y * 32, c0 = blockIdx.x * 32;
#pragma unroll
  for (int i = 0; i < 32; i += 8)
    tile[ty + i][tx] = in[(size_t)(r0 + ty + i) * C + c0 + tx];
  __syncthreads();
#pragma unroll
  for (int i = 0; i < 32; i += 8)
    out[(size_t)(c0 + ty + i) * R + r0 + tx] = f2bf(tile[tx][ty + i]);
}

// =====================================================================================
// 256x256 8-phase GEMM, register-held quadrant fragments, half-tile staging,
// counted vmcnt(4) waits placed BEFORE end-of-phase barriers (race-free ledger):
//   H1 = units {A0,B0,A1,B1} (read ph1/ph4), issued at ph1 of previous tile
//   H2 = units {A2,B2,A3,B3} (read ph2/ph3), issued at ph2 of previous tile
//   ph1-end VM4: pool = H2(t)+H1(t+1) -> H2(t) landed before ph2 reads it
//   ph4-end VM4: pool = H1(t+1)+H2(t+1) -> H1(t+1) landed before next ph1 reads it
// Every dependent ds_read is issued after a barrier that follows its covering wait.
// =====================================================================================

#define BARRIER __builtin_amdgcn_s_barrier()
#define LGKM0 asm volatile("s_waitcnt lgkmcnt(0)" ::: "memory")
#define PRIO1 __builtin_amdgcn_s_setprio(1)
#define PRIO0 __builtin_amdgcn_s_setprio(0)
#define VM4 asm volatile("s_waitcnt vmcnt(4)" ::: "memory")
#define VM0 asm volatile("s_waitcnt vmcnt(0)" ::: "memory")
#define NOPSTMT do {} while (0)

#define RD_A(dst, PR, QM) do { _Pragma("unroll")                                         \
  for (int mi2 = 0; mi2 < 4; ++mi2) {                                                    \
    dst[mi2][0] = *(const s16x8*)(smem + (PR)*32768 + (QM)*16384 + mi2*2048 + aOff0);    \
    dst[mi2][1] = *(const s16x8*)(smem + (PR)*32768 + (QM)*16384 + mi2*2048 + aOff1);    \
  } } while (0)

#define RD_B(dst, PR, QN) do { _Pragma("unroll")                                         \
  for (int ni2 = 0; ni2 < 2; ++ni2) {                                                    \
    dst[ni2][0] = *(const s16x8*)(smem + 65536 + (PR)*32768 + (QN)*16384 + ni2*2048 + bOff0); \
    dst[ni2][1] = *(const s16x8*)(smem + 65536 + (PR)*32768 + (QN)*16384 + ni2*2048 + bOff1); \
  } } while (0)

#define MFMA_Q(QM, QN, Af, Bf) do { _Pragma("unroll")                                    \
  for (int ks = 0; ks < 2; ++ks) { _Pragma("unroll")                                     \
    for (int mi2 = 0; mi2 < 4; ++mi2) { _Pragma("unroll")                                \
      for (int ni2 = 0; ni2 < 2; ++ni2)                                                  \
        acc[(QM)*4+mi2][(QN)*2+ni2] =                                                    \
            MFMA_BF16(Af[mi2][ks], Bf[ni2][ks], acc[(QM)*4+mi2][(QN)*2+ni2]);            \
  } } } while (0)

#define STAGE_PAIR(x, PW, kn) do {                                                       \
  gll16(srcA[x] + (kn), smem + (PW)*32768 + (x)*8192 + tt*16);                           \
  gll16(srcB[x] + (kn), smem + 65536 + (PW)*32768 + (x)*8192 + tt*16);                   \
} while (0)

#define STAGE_H1(PW, kn) do { STAGE_PAIR(0, PW, kn); STAGE_PAIR(1, PW, kn); } while (0)
#define STAGE_H2(PW, kn) do { STAGE_PAIR(2, PW, kn); STAGE_PAIR(3, PW, kn); } while (0)

// phase: RDs; optional stage; pre-MFMA barrier; lgkm drain; MFMA; optional wait; end barrier
#define TILE_BODY(PR, ST1, ST2, W1, W4) do {                                             \
  s16x8 a0[4][2], a1[4][2], b0[2][2], b1[2][2];                                          \
  /* ph1: Q00 — reads H1(t) (covered by prev ph4-end VM4+barrier) */                     \
  RD_A(a0, PR, 0); RD_B(b0, PR, 0);                                                      \
  ST1;                                                                                   \
  BARRIER; LGKM0; PRIO1; MFMA_Q(0, 0, a0, b0); PRIO0;                                    \
  W1; BARRIER;                                                                           \
  /* ph2: Q01 — reads B2,B3 of H2(t) (covered by W1+barrier) */                          \
  RD_B(b1, PR, 1);                                                                       \
  ST2;                                                                                   \
  BARRIER; LGKM0; PRIO1; MFMA_Q(0, 1, a0, b1); PRIO0; BARRIER;                           \
  /* ph3: Q11 — reads A2,A3 of H2(t) */                                                  \
  RD_A(a1, PR, 1);                                                                       \
  BARRIER; LGKM0; PRIO1; MFMA_Q(1, 1, a1, b1); PRIO0; BARRIER;                           \
  /* ph4: Q10 — re-reads B0,B1 of H1(t) */                                               \
  RD_B(b0, PR, 0);                                                                       \
  BARRIER; LGKM0; PRIO1; MFMA_Q(1, 0, a1, b0); PRIO0;                                    \
  W4; BARRIER;                                                                           \
} while (0)

#define TILE_MAIN(PR, PW, kn) TILE_BODY(PR, STAGE_H1(PW, kn), STAGE_H2(PW, kn), VM4, VM4)
#define TILE_LAST(PR) TILE_BODY(PR, NOPSTMT, NOPSTMT, VM0, NOPSTMT)

template<int EPI>
__global__ __launch_bounds__(512, 2)
void gemm256_kernel(const u16* __restrict__ A, const u16* __restrict__ Bt,
                    float* __restrict__ Cf, u16* __restrict__ Cq,
                    u16* __restrict__ Ck, u16* __restrict__ Cvt,
                    int N, int K) {
  __shared__ __align__(16) char smem[131072];
  const int tt = threadIdx.x;
  const int w = tt >> 6, l = tt & 63;
  const int li = l & 15, g = l >> 4;
  const int wm = w >> 2, wn = w & 3;

  // XCD-aware bijective swizzle (grid block-count is a multiple of 8)
  const int gx = gridDim.x;
  const int nwg = gx * gridDim.y;
  int id = blockIdx.y * gx + blockIdx.x;
  id = (id & 7) * (nwg >> 3) + (id >> 3);
  const int bn = id % gx, bm = id / gx;

  f32x4 acc[8][4];
#pragma unroll
  for (int i = 0; i < 8; ++i)
#pragma unroll
    for (int j = 0; j < 4; ++j) acc[i][j] = f4zero();

  // ---- staging source pointers (pre-permuted rows + inverse granule swizzle) ----
  const int q8 = (((tt & 7) ^ ((tt >> 3) & 7)) * 8);
  const u16* srcA[4];
  const u16* srcB[4];
#pragma unroll
  for (int x = 0; x < 4; ++x) {
    const int arow = (x & 1) * 128 + (x >> 1) * 64 + (tt >> 3);
    srcA[x] = A + (size_t)(bm * 256 + arow) * K + q8;
    const int rho = x * 64 + (tt >> 3);
    const int qn_ = rho >> 7, rem = rho & 127;
    const int wn_ = rem >> 5, rr = rem & 31;
    const int brow = wn_ * 64 + qn_ * 32 + rr;
    srcB[x] = Bt + (size_t)(bn * 256 + brow) * K + q8;
  }

  // ---- ds_read per-thread byte offsets (granule XOR by row&7 == li&7) ----
  const int gr0 = (g ^ (li & 7)) * 16;
  const int aOff0 = wm * 8192 + li * 128 + gr0;
  const int aOff1 = aOff0 ^ 64;
  const int bOff0 = wn * 4096 + li * 128 + gr0;
  const int bOff1 = bOff0 ^ 64;

  // ---- prologue: stage tile 0 into parity 0, full drain + barrier ----
  STAGE_H1(0, 0);
  STAGE_H2(0, 0);
  VM0;
  BARRIER;

  // ---- main loop: 64 K-tiles (K == 4096), 2 per iteration ----
  for (int t2 = 0; t2 < 62; t2 += 2) {
    TILE_MAIN(0, 1, (t2 + 1) * 64);
    TILE_MAIN(1, 0, (t2 + 2) * 64);
  }
  TILE_MAIN(0, 1, 63 * 64);   // tile 62, stages tile 63
  TILE_LAST(1);               // tile 63

  // ---- epilogue ----
#pragma unroll
  for (int mi = 0; mi < 8; ++mi) {
#pragma unroll
    for (int ni = 0; ni < 4; ++ni) {
      const int row0 = bm * 256 + wm * 128 + mi * 16 + g * 4;
      const int col = bn * 256 + wn * 64 + ni * 16 + li;
#pragma unroll
      for (int r = 0; r < 4; ++r) {
        const int m = row0 + r;
        const float v = acc[mi][ni][r];
        if (EPI == 0) {
          Cf[(size_t)m * N + col] = v;
        } else {
          const int bb2 = m >> 11, s = m & 2047;
          const int kt = s >> 5;
          const size_t tb = (size_t)(bb2 * 64 + kt);
          if (col < 4096) {
            Cq[(size_t)m * 4096 + col] = f2bf(v);
          } else if (col < 4224) {
            const int d = col - 4096, kr = s & 31;
            const int mk = kr >> 4, lii = kr & 15;
            const int kk = d >> 5, gg = (d >> 3) & 3, e = d & 7;
            Ck[(tb * 8 + mk * 4 + kk) * 512 + (gg * 16 + lii) * 8 + e] = f2bf(v);
          } else {
            const int d = col - 4224, kp = s & 31;
            const int mf = d >> 4, lii = d & 15;
            const int gg = kp >> 3, e = kp & 7;
            Cvt[(tb * 8 + mf) * 512 + (gg * 16 + lii) * 8 + e] = f2bf(v);
          }
        }
      }
    }
  }
}

// ---------------- flash attention (MQA) ----------------
// 1 wave/block; block p handles q-tiles {63-p, p} (uniform 66 tile-units).
// K double-buffered in registers; V issued at tile top; fragment-linear K/V loads.

__device__ __forceinline__ void load_ktile(s16x8 (&dst)[8], const u16* kf, size_t tb, int l) {
#pragma unroll
  for (int f = 0; f < 8; ++f)
    dst[f] = *(const s16x8*)&kf[(tb * 8 + f) * 512 + l * 8];
}

template<bool DIAG>
__device__ __forceinline__ void attn_tile(
    int kt, const u16* kf, const u16* vf, size_t bb64, int l, int li, int g,
    s16x8 (&use)[8], s16x8 (&fill)[8], bool do_fill,
    const s16x8 (&bq)[2][4], f32x4 (&acc)[8][2],
    float (&m_)[2], float (&lp)[2], float (&bias)[2],
    float c1, const float (&cjr)[8], float bstep, u16 (*Pw)[40]) {
  const size_t tb = bb64 + kt;
  s16x8 vr[8];
#pragma unroll
  for (int f = 0; f < 8; ++f)
    vr[f] = *(const s16x8*)&vf[(tb * 8 + f) * 512 + l * 8];
  if (do_fill) load_ktile(fill, kf, tb - 1, l);

  f32x4 sc[2][2];
  sc[0][0] = f4zero(); sc[0][1] = f4zero(); sc[1][0] = f4zero(); sc[1][1] = f4zero();
#pragma unroll
  for (int kk = 0; kk < 4; ++kk)
#pragma unroll
    for (int mk = 0; mk < 2; ++mk) {
      sc[mk][0] = MFMA_BF16(use[mk * 4 + kk], bq[0][kk], sc[mk][0]);
      sc[mk][1] = MFMA_BF16(use[mk * 4 + kk], bq[1][kk], sc[mk][1]);
    }

#pragma unroll
  for (int nq = 0; nq < 2; ++nq) {
    float sv[8];
    float pm = -3e38f;
    if (DIAG) {
#pragma unroll
      for (int mk = 0; mk < 2; ++mk)
#pragma unroll
        for (int r = 0; r < 4; ++r) {
          const int kd = mk * 16 + g * 4 + r - (nq * 16 + li);
          float s = fmaf(sc[mk][nq][r], c1, bias[nq] + cjr[mk * 4 + r]);
          s = (kd <= 0) ? s : -1e30f;
          sv[mk * 4 + r] = s;
          pm = fmaxf(pm, s);
        }
      pm = fmaxf(pm, __shfl_xor(pm, 16));
      pm = fmaxf(pm, __shfl_xor(pm, 32));
      m_[nq] = pm;
    } else {
#pragma unroll
      for (int mk = 0; mk < 2; ++mk)
#pragma unroll
        for (int r = 0; r < 4; ++r) {
          float s = fmaf(sc[mk][nq][r], c1, bias[nq] + cjr[mk * 4 + r]);
          sv[mk * 4 + r] = s;
          pm = fmaxf(pm, s);
        }
      if (__any(pm > m_[nq])) {
        pm = fmaxf(pm, __shfl_xor(pm, 16));
        pm = fmaxf(pm, __shfl_xor(pm, 32));
        const float nm = fmaxf(m_[nq], pm);
        const float scale = exp2f(m_[nq] - nm);
#pragma unroll
        for (int mf = 0; mf < 8; ++mf) acc[mf][nq] *= scale;
        lp[nq] *= scale;
        m_[nq] = nm;
      }
    }
    const float mref = m_[nq];
    float e[8];
#pragma unroll
    for (int j = 0; j < 8; ++j) e[j] = exp2f(sv[j] - mref);
    lp[nq] += ((e[0] + e[1]) + (e[2] + e[3])) + ((e[4] + e[5]) + (e[6] + e[7]));
#pragma unroll
    for (int mk = 0; mk < 2; ++mk) {
      uint2 wv;
      wv.x = pkbf(e[mk * 4 + 0], e[mk * 4 + 1]);
      wv.y = pkbf(e[mk * 4 + 2], e[mk * 4 + 3]);
      *reinterpret_cast<uint2*>(&Pw[nq * 16 + li][mk * 16 + g * 4]) = wv;
    }
    bias[nq] -= bstep;
  }

  s16x8 pb0 = *(const s16x8*)&Pw[li][g * 8];
  s16x8 pb1 = *(const s16x8*)&Pw[16 + li][g * 8];
#pragma unroll
  for (int mf = 0; mf < 8; ++mf) {
    acc[mf][0] = MFMA_BF16(vr[mf], pb0, acc[mf][0]);
    acc[mf][1] = MFMA_BF16(vr[mf], pb1, acc[mf][1]);
  }
}

__device__ __forceinline__ void attn_qtile(
    int qt, int h, int b, const u16* qbuf, const u16* kf, const u16* vf,
    u16* obuf, int l, int li, int g, float c1, float sl2, u16 (*Pw)[40]) {
  const int S = 2048;
  const int q0 = qt * 32;
  const size_t bb64 = (size_t)b * 64;

  s16x8 bq[2][4];
#pragma unroll
  for (int nq = 0; nq < 2; ++nq)
#pragma unroll
    for (int kk = 0; kk < 4; ++kk)
      bq[nq][kk] = *(const s16x8*)&qbuf[(size_t)(b * S + q0 + nq * 16 + li) * 4096
                                        + h * 128 + kk * 32 + g * 8];

  f32x4 acc[8][2];
#pragma unroll
  for (int mf = 0; mf < 8; ++mf) { acc[mf][0] = f4zero(); acc[mf][1] = f4zero(); }
  float m_[2] = {-3e38f, -3e38f};
  float lp[2] = {0.f, 0.f};

  float cjr[8];
#pragma unroll
  for (int j = 0; j < 8; ++j) cjr[j] = sl2 * (float)((j >> 2) * 16 + (j & 3));
  float bias[2];
#pragma unroll
  for (int nq = 0; nq < 2; ++nq)
    bias[nq] = sl2 * (float)(g * 4 - nq * 16 - li);
  const float bstep = sl2 * 32.f;

  s16x8 kA[8], kB[8];
  load_ktile(kA, kf, bb64 + qt, l);
  attn_tile<true>(qt, kf, vf, bb64, l, li, g, kA, kB, qt >= 1,
                  bq, acc, m_, lp, bias, c1, cjr, bstep, Pw);
  int kt = qt - 1;
  while (kt >= 1) {
    attn_tile<false>(kt, kf, vf, bb64, l, li, g, kB, kA, true,
                     bq, acc, m_, lp, bias, c1, cjr, bstep, Pw);
    attn_tile<false>(kt - 1, kf, vf, bb64, l, li, g, kA, kB, kt >= 2,
                     bq, acc, m_, lp, bias, c1, cjr, bstep, Pw);
    kt -= 2;
  }
  if (kt == 0)
    attn_tile<false>(0, kf, vf, bb64, l, li, g, kB, kA, false,
                     bq, acc, m_, lp, bias, c1, cjr, bstep, Pw);

#pragma unroll
  for (int nq = 0; nq < 2; ++nq) {
    float ls = lp[nq];
    ls += __shfl_xor(ls, 16);
    ls += __shfl_xor(ls, 32);
    const float inv = 1.f / ls;
    const size_t rowbase = (size_t)(b * S + q0 + nq * 16 + li) * 4096 + h * 128;
#pragma unroll
    for (int mf = 0; mf < 8; ++mf) {
      f32x4 v = acc[mf][nq];
      uint2 wv;
      wv.x = pkbf(v[0] * inv, v[1] * inv);
      wv.y = pkbf(v[2] * inv, v[3] * inv);
      *reinterpret_cast<uint2*>(&obuf[rowbase + mf * 16 + g * 4]) = wv;
    }
  }
}

__global__ __launch_bounds__(64, 2)
void attn_kernel(const u16* __restrict__ qbuf, const u16* __restrict__ kf,
                 const u16* __restrict__ vf, u16* __restrict__ obuf) {
  const int p = blockIdx.x, h = blockIdx.y, b = blockIdx.z;
  const int l = threadIdx.x, li = l & 15, g = l >> 4;
  const float L2E = 1.4426950408889634f;
  const float slope = exp2f(-0.25f * (float)(h + 1));
  const float c1 = 0.08838834764831845f * L2E;
  const float sl2 = slope * L2E;
  __shared__ __align__(16) u16 P[32][40];
  attn_qtile(63 - p, h, b, qbuf, kf, vf, obuf, l, li, g, c1, sl2, P);
  attn_qtile(p, h, b, qbuf, kf, vf, obuf, l, li, g, c1, sl2, P);
}

// ---------------- launch ----------------
extern "C" void kernel_launch(void* const* d_in, const int* in_sizes, int n_in,
                              void* d_out, int out_size, void* d_ws, size_t ws_size,
                              hipStream_t stream) {
  (void)in_sizes; (void)n_in; (void)out_size; (void)ws_size;
  const float* hidden = (const float*)d_in[0];
  const float* w_qkv = (const float*)d_in[1];
  const float* w_c = (const float*)d_in[2];
  float* out = (float*)d_out;
  char* ws = (char*)d_ws;

  // workspace layout (100 MB total)
  u16* hid_bf = (u16*)(ws + 0);            // 32 MB  (B*S,4096) bf16; reused as attn out
  u16* wT     = (u16*)(ws + 33554432);     // 34 MB  w_qkv^T then w_c^T (N,K) bf16
  u16* qbuf   = (u16*)(ws + 69206016);     // 32 MB  (B*S,4096) bf16
  u16* kbuf   = (u16*)(ws + 102760448);    // 1 MB   K fragment-linear
  u16* vtbuf  = (u16*)(ws + 103809024);    // 1 MB   V fragment-linear

  cvt_bf16_kernel<<<16384, 256, 0, stream>>>((const float4*)hidden, hid_bf, 4194304);
  transpose_cvt_kernel<<<dim3(136, 128), dim3(32, 8), 0, stream>>>(w_qkv, wT, 4096, 4352);
  gemm256_kernel<1><<<dim3(17, 16), 512, 0, stream>>>(hid_bf, wT, nullptr, qbuf, kbuf, vtbuf,
                                                      4352, 4096);
  attn_kernel<<<dim3(32, 32, 2), 64, 0, stream>>>(qbuf, kbuf, vtbuf, hid_bf);
  transpose_cvt_kernel<<<dim3(128, 128), dim3(32, 8), 0, stream>>>(w_c, wT, 4096, 4096);
  gemm256_kernel<0><<<dim3(16, 16), 512, 0, stream>>>(hid_bf, wT, out, nullptr, nullptr, nullptr,
                                                      4096, 4096);
}

// Round 8
// 485.796 us; speedup vs baseline: 1.8165x; 1.0372x over previous
//
#include <hip/hip_runtime.h>
#include <hip/hip_bf16.h>

typedef unsigned short u16;
typedef unsigned int u32;
typedef __attribute__((ext_vector_type(8))) short s16x8;
typedef __attribute__((ext_vector_type(4))) float f32x4;

#define MFMA_BF16(a, b, c) __builtin_amdgcn_mfma_f32_16x16x32_bf16(a, b, c, 0, 0, 0)

__device__ __forceinline__ u16 f2bf(float f) {
  union { float f; u32 u; } c; c.f = f;
  return (u16)((c.u + 0x7FFFu + ((c.u >> 16) & 1u)) >> 16);
}

__device__ __forceinline__ u32 pkbf(float a, float b) {
  float2 t; t.x = a; t.y = b;
  __hip_bfloat162 h = __float22bfloat162_rn(t);
  union { __hip_bfloat162 h; u32 u; } c; c.h = h; return c.u;
}

__device__ __forceinline__ void gll16(const void* g, void* l) {
  __builtin_amdgcn_global_load_lds((const __attribute__((address_space(1))) void*)g,
                                   (__attribute__((address_space(3))) void*)l, 16, 0, 0);
}

__device__ __forceinline__ f32x4 f4zero() { f32x4 z = {0.f, 0.f, 0.f, 0.f}; return z; }

// ---------------- prep: f32 -> bf16 convert ----------------
__global__ void cvt_bf16_kernel(const float4* __restrict__ in, u16* __restrict__ out, int n4) {
  int i = blockIdx.x * 256 + threadIdx.x;
  if (i >= n4) return;
  float4 v = in[i];
  uint2 w;
  w.x = (u32)f2bf(v.x) | ((u32)f2bf(v.y) << 16);
  w.y = (u32)f2bf(v.z) | ((u32)f2bf(v.w) << 16);
  *reinterpret_cast<uint2*>(out + (size_t)i * 4) = w;
}

// ---------------- prep: transpose + convert (R x C f32 -> C x R bf16) ----------------
__global__ void transpose_cvt_kernel(const float* __restrict__ in, u16* __restrict__ out,
                                     int R, int C) {
  __shared__ float tile[32][33];
  int tx = threadIdx.x, ty = threadIdx.y;
  int r0 = blockIdx.y * 32, c0 = blockIdx.x * 32;
#pragma unroll
  for (int i = 0; i < 32; i += 8)
    tile[ty + i][tx] = in[(size_t)(r0 + ty + i) * C + c0 + tx];
  __syncthreads();
#pragma unroll
  for (int i = 0; i < 32; i += 8)
    out[(size_t)(c0 + ty + i) * R + r0 + tx] = f2bf(tile[tx][ty + i]);
}

// =====================================================================================
// 256x256 8-phase GEMM, register-held quadrant fragments, spread half-unit staging
// (one 2-load unit per phase), counted vmcnt before end-of-phase barriers.
// EPI 1 additionally fuses the 256-col KV strip (cols 4096..4351) so the grid is
// exactly 16x16 = 256 blocks (1/CU, no second scheduling round):
//   block (bm,bn) computes KV rows [bm*256+bn*16, +16) x 256 via the LDS A-slice
//   (already staged) + KV B-frags loaded straight from wT (L2-resident, 2 MB).
// vmcnt ledger (units = 2 loads):
//   ph1: [EPI1: 4 bkv reg-loads] + stage U0(t+1); ph2: U1; ph3: U2; ph4: U3
//   ph1-end: drain U2(t),U3(t)  -> VM2 (EPI0) / VM6 (EPI1, leaves bkv+U0)
//   ph4-end: drain U0(t+1),U1(t+1) -> VM4   (bkv drained by compiler wait at ph4 use)
// LDS A row map: global row G = wm*128 + QM*64 + mi2*16 + li lives at byte
//   QM*16384 + wm*8192 + mi2*2048 + li*128  (KV slice: G=bn*16+li ->
//   QM'=(bn>>2)&1 -> *16384, wm'=bn>>3 -> *8192, mi2'=bn&3 -> *2048).
// =====================================================================================

#define BARRIER __builtin_amdgcn_s_barrier()
#define LGKM0 asm volatile("s_waitcnt lgkmcnt(0)" ::: "memory")
#define PRIO1 __builtin_amdgcn_s_setprio(1)
#define PRIO0 __builtin_amdgcn_s_setprio(0)
#define VM6 asm volatile("s_waitcnt vmcnt(6)" ::: "memory")
#define VM4 asm volatile("s_waitcnt vmcnt(4)" ::: "memory")
#define VM2 asm volatile("s_waitcnt vmcnt(2)" ::: "memory")
#define VM0 asm volatile("s_waitcnt vmcnt(0)" ::: "memory")
#define NOPSTMT do {} while (0)
#define W1EPI do { if constexpr (EPI == 1) { VM6; } else { VM2; } } while (0)

#define RD_A(dst, PR, QM) do { _Pragma("unroll")                                         \
  for (int mi2 = 0; mi2 < 4; ++mi2) {                                                    \
    dst[mi2][0] = *(const s16x8*)(smem + (PR)*32768 + (QM)*16384 + mi2*2048 + aOff0);    \
    dst[mi2][1] = *(const s16x8*)(smem + (PR)*32768 + (QM)*16384 + mi2*2048 + aOff1);    \
  } } while (0)

#define RD_B(dst, PR, QN) do { _Pragma("unroll")                                         \
  for (int ni2 = 0; ni2 < 2; ++ni2) {                                                    \
    dst[ni2][0] = *(const s16x8*)(smem + 65536 + (PR)*32768 + (QN)*16384 + ni2*2048 + bOff0); \
    dst[ni2][1] = *(const s16x8*)(smem + 65536 + (PR)*32768 + (QN)*16384 + ni2*2048 + bOff1); \
  } } while (0)

#define MFMA_Q(QM, QN, Af, Bf) do { _Pragma("unroll")                                    \
  for (int ks = 0; ks < 2; ++ks) { _Pragma("unroll")                                     \
    for (int mi2 = 0; mi2 < 4; ++mi2) { _Pragma("unroll")                                \
      for (int ni2 = 0; ni2 < 2; ++ni2)                                                  \
        acc[(QM)*4+mi2][(QN)*2+ni2] =                                                    \
            MFMA_BF16(Af[mi2][ks], Bf[ni2][ks], acc[(QM)*4+mi2][(QN)*2+ni2]);            \
  } } } while (0)

#define STAGE_PAIR(x, PW, kn) do {                                                       \
  gll16(srcA[x] + (kn), smem + (PW)*32768 + (x)*8192 + tt*16);                           \
  gll16(srcB[x] + (kn), smem + 65536 + (PW)*32768 + (x)*8192 + tt*16);                   \
} while (0)

#define TILE_BODY(PR, KB, S1, S2, S3, S4, W1, W4) do {                                   \
  s16x8 a0[4][2], a1[4][2], b0[2][2], b1[2][2];                                          \
  s16x8 bkv[2][2]; s16x8 sa[2];                                                          \
  /* ph1: Q00 */                                                                         \
  RD_A(a0, PR, 0); RD_B(b0, PR, 0);                                                      \
  if constexpr (EPI == 1) {                                                              \
    const u16* kvp = Bt + (size_t)(4096 + w * 32 + li) * K + (KB) + g * 8;               \
    bkv[0][0] = *(const s16x8*)(kvp);                                                    \
    bkv[0][1] = *(const s16x8*)(kvp + 32);                                               \
    bkv[1][0] = *(const s16x8*)(kvp + (size_t)16 * K);                                   \
    bkv[1][1] = *(const s16x8*)(kvp + (size_t)16 * K + 32);                              \
  }                                                                                      \
  S1;                                                                                    \
  BARRIER; LGKM0; PRIO1; MFMA_Q(0, 0, a0, b0); PRIO0;                                    \
  W1; BARRIER;                                                                           \
  /* ph2: Q01 */                                                                         \
  RD_B(b1, PR, 1);                                                                       \
  S2;                                                                                    \
  BARRIER; LGKM0; PRIO1; MFMA_Q(0, 1, a0, b1); PRIO0; BARRIER;                           \
  /* ph3: Q11 */                                                                         \
  RD_A(a1, PR, 1);                                                                       \
  S3;                                                                                    \
  BARRIER; LGKM0; PRIO1; MFMA_Q(1, 1, a1, b1); PRIO0; BARRIER;                           \
  /* ph4: Q10 + KV strip */                                                              \
  RD_B(b0, PR, 0);                                                                       \
  if constexpr (EPI == 1) {                                                              \
    sa[0] = *(const s16x8*)(smem + (PR)*32768 + aKV);                                    \
    sa[1] = *(const s16x8*)(smem + (PR)*32768 + (aKV ^ 64));                             \
  }                                                                                      \
  S4;                                                                                    \
  BARRIER; LGKM0; PRIO1; MFMA_Q(1, 0, a1, b0);                                           \
  if constexpr (EPI == 1) { _Pragma("unroll")                                            \
    for (int ks2 = 0; ks2 < 2; ++ks2) { _Pragma("unroll")                                \
      for (int cs2 = 0; cs2 < 2; ++cs2)                                                  \
        acc_kv[cs2] = MFMA_BF16(sa[ks2], bkv[cs2][ks2], acc_kv[cs2]);                    \
  } }                                                                                    \
  PRIO0; W4; BARRIER;                                                                    \
} while (0)

#define TILE_MAIN(PR, PW, T) TILE_BODY(PR, (T)*64,                                       \
  STAGE_PAIR(0, PW, ((T)+1)*64), STAGE_PAIR(1, PW, ((T)+1)*64),                          \
  STAGE_PAIR(2, PW, ((T)+1)*64), STAGE_PAIR(3, PW, ((T)+1)*64), W1EPI, VM4)
#define TILE_LAST(PR, T) TILE_BODY(PR, (T)*64, NOPSTMT, NOPSTMT, NOPSTMT, NOPSTMT, VM0, NOPSTMT)

template<int EPI>
__global__ __launch_bounds__(512, 2)
void gemm256_kernel(const u16* __restrict__ A, const u16* __restrict__ Bt,
                    float* __restrict__ Cf, u16* __restrict__ Cq,
                    u16* __restrict__ Ck, u16* __restrict__ Cvt,
                    int N, int K) {
  __shared__ __align__(16) char smem[131072];
  const int tt = threadIdx.x;
  const int w = tt >> 6, l = tt & 63;
  const int li = l & 15, g = l >> 4;
  const int wm = w >> 2, wn = w & 3;

  // XCD-aware bijective swizzle (grid block-count is a multiple of 8)
  const int gx = gridDim.x;
  const int nwg = gx * gridDim.y;
  int id = blockIdx.y * gx + blockIdx.x;
  id = (id & 7) * (nwg >> 3) + (id >> 3);
  const int bn = id % gx, bm = id / gx;

  f32x4 acc[8][4];
#pragma unroll
  for (int i = 0; i < 8; ++i)
#pragma unroll
    for (int j = 0; j < 4; ++j) acc[i][j] = f4zero();
  f32x4 acc_kv[2];
  acc_kv[0] = f4zero(); acc_kv[1] = f4zero();

  // ---- staging source pointers (pre-permuted rows + inverse granule swizzle) ----
  const int q8 = (((tt & 7) ^ ((tt >> 3) & 7)) * 8);
  const u16* srcA[4];
  const u16* srcB[4];
#pragma unroll
  for (int x = 0; x < 4; ++x) {
    const int arow = (x & 1) * 128 + (x >> 1) * 64 + (tt >> 3);
    srcA[x] = A + (size_t)(bm * 256 + arow) * K + q8;
    const int rho = x * 64 + (tt >> 3);
    const int qn_ = rho >> 7, rem = rho & 127;
    const int wn_ = rem >> 5, rr = rem & 31;
    const int brow = wn_ * 64 + qn_ * 32 + rr;
    srcB[x] = Bt + (size_t)(bn * 256 + brow) * K + q8;
  }

  // ---- ds_read per-thread byte offsets (granule XOR by row&7 == li&7) ----
  const int gr0 = (g ^ (li & 7)) * 16;
  const int aOff0 = wm * 8192 + li * 128 + gr0;
  const int aOff1 = aOff0 ^ 64;
  const int bOff0 = wn * 4096 + li * 128 + gr0;
  const int bOff1 = bOff0 ^ 64;
  // KV strip A-slice: global rows bn*16 + li -> QM'=(bn>>2)&1, wm'=bn>>3, mi2'=bn&3
  const int aKV = ((bn >> 2) & 1) * 16384 + (bn >> 3) * 8192 + (bn & 3) * 2048
                  + li * 128 + gr0;

  // ---- prologue: stage tile 0 into parity 0, full drain + barrier ----
#pragma unroll
  for (int x = 0; x < 4; ++x) STAGE_PAIR(x, 0, 0);
  VM0;
  BARRIER;

  // ---- main loop: 64 K-tiles (K == 4096), 2 per iteration ----
  for (int t2 = 0; t2 < 62; t2 += 2) {
    TILE_MAIN(0, 1, t2);
    TILE_MAIN(1, 0, t2 + 1);
  }
  TILE_MAIN(0, 1, 62);   // tile 62, stages tile 63
  TILE_LAST(1, 63);      // tile 63

  // ---- epilogue ----
#pragma unroll
  for (int mi = 0; mi < 8; ++mi) {
#pragma unroll
    for (int ni = 0; ni < 4; ++ni) {
      const int row0 = bm * 256 + wm * 128 + mi * 16 + g * 4;
      const int col = bn * 256 + wn * 64 + ni * 16 + li;
#pragma unroll
      for (int r = 0; r < 4; ++r) {
        const int m = row0 + r;
        const float v = acc[mi][ni][r];
        if (EPI == 0) {
          Cf[(size_t)m * N + col] = v;
        } else {
          Cq[(size_t)m * 4096 + col] = f2bf(v);
        }
      }
    }
  }
  if constexpr (EPI == 1) {
    // KV strip epilogue: rows bm*256 + bn*16 + g*4 + r, cols 4096 + w*32 + cs*16 + li
#pragma unroll
    for (int cs = 0; cs < 2; ++cs) {
      const int col = 4096 + w * 32 + cs * 16 + li;
#pragma unroll
      for (int r = 0; r < 4; ++r) {
        const int m = bm * 256 + bn * 16 + g * 4 + r;
        const float v = acc_kv[cs][r];
        const int bb2 = m >> 11, s = m & 2047;
        const int kt = s >> 5;
        const size_t tb = (size_t)(bb2 * 64 + kt);
        if (col < 4224) {
          const int d = col - 4096, kr = s & 31;
          const int mk = kr >> 4, lii = kr & 15;
          const int kk = d >> 5, gg = (d >> 3) & 3, e = d & 7;
          Ck[(tb * 8 + mk * 4 + kk) * 512 + (gg * 16 + lii) * 8 + e] = f2bf(v);
        } else {
          const int d = col - 4224, kp = s & 31;
          const int mf = d >> 4, lii = d & 15;
          const int gg = kp >> 3, e = kp & 7;
          Cvt[(tb * 8 + mf) * 512 + (gg * 16 + lii) * 8 + e] = f2bf(v);
        }
      }
    }
  }
}

// ---------------- flash attention (MQA) ----------------
// 1 wave/block; block p handles q-tiles {63-p, p} (uniform 66 tile-units).
// K double-buffered in registers; V issued at tile top; fragment-linear K/V loads.

__device__ __forceinline__ void load_ktile(s16x8 (&dst)[8], const u16* kf, size_t tb, int l) {
#pragma unroll
  for (int f = 0; f < 8; ++f)
    dst[f] = *(const s16x8*)&kf[(tb * 8 + f) * 512 + l * 8];
}

template<bool DIAG>
__device__ __forceinline__ void attn_tile(
    int kt, const u16* kf, const u16* vf, size_t bb64, int l, int li, int g,
    s16x8 (&use)[8], s16x8 (&fill)[8], bool do_fill,
    const s16x8 (&bq)[2][4], f32x4 (&acc)[8][2],
    float (&m_)[2], float (&lp)[2], float (&bias)[2],
    float c1, const float (&cjr)[8], float bstep, u16 (*Pw)[40]) {
  const size_t tb = bb64 + kt;
  s16x8 vr[8];
#pragma unroll
  for (int f = 0; f < 8; ++f)
    vr[f] = *(const s16x8*)&vf[(tb * 8 + f) * 512 + l * 8];
  if (do_fill) load_ktile(fill, kf, tb - 1, l);

  f32x4 sc[2][2];
  sc[0][0] = f4zero(); sc[0][1] = f4zero(); sc[1][0] = f4zero(); sc[1][1] = f4zero();
#pragma unroll
  for (int kk = 0; kk < 4; ++kk)
#pragma unroll
    for (int mk = 0; mk < 2; ++mk) {
      sc[mk][0] = MFMA_BF16(use[mk * 4 + kk], bq[0][kk], sc[mk][0]);
      sc[mk][1] = MFMA_BF16(use[mk * 4 + kk], bq[1][kk], sc[mk][1]);
    }

#pragma unroll
  for (int nq = 0; nq < 2; ++nq) {
    float sv[8];
    float pm = -3e38f;
    if (DIAG) {
#pragma unroll
      for (int mk = 0; mk < 2; ++mk)
#pragma unroll
        for (int r = 0; r < 4; ++r) {
          const int kd = mk * 16 + g * 4 + r - (nq * 16 + li);
          float s = fmaf(sc[mk][nq][r], c1, bias[nq] + cjr[mk * 4 + r]);
          s = (kd <= 0) ? s : -1e30f;
          sv[mk * 4 + r] = s;
          pm = fmaxf(pm, s);
        }
      pm = fmaxf(pm, __shfl_xor(pm, 16));
      pm = fmaxf(pm, __shfl_xor(pm, 32));
      m_[nq] = pm;
    } else {
#pragma unroll
      for (int mk = 0; mk < 2; ++mk)
#pragma unroll
        for (int r = 0; r < 4; ++r) {
          float s = fmaf(sc[mk][nq][r], c1, bias[nq] + cjr[mk * 4 + r]);
          sv[mk * 4 + r] = s;
          pm = fmaxf(pm, s);
        }
      if (__any(pm > m_[nq])) {
        pm = fmaxf(pm, __shfl_xor(pm, 16));
        pm = fmaxf(pm, __shfl_xor(pm, 32));
        const float nm = fmaxf(m_[nq], pm);
        const float scale = exp2f(m_[nq] - nm);
#pragma unroll
        for (int mf = 0; mf < 8; ++mf) acc[mf][nq] *= scale;
        lp[nq] *= scale;
        m_[nq] = nm;
      }
    }
    const float mref = m_[nq];
    float e[8];
#pragma unroll
    for (int j = 0; j < 8; ++j) e[j] = exp2f(sv[j] - mref);
    lp[nq] += ((e[0] + e[1]) + (e[2] + e[3])) + ((e[4] + e[5]) + (e[6] + e[7]));
#pragma unroll
    for (int mk = 0; mk < 2; ++mk) {
      uint2 wv;
      wv.x = pkbf(e[mk * 4 + 0], e[mk * 4 + 1]);
      wv.y = pkbf(e[mk * 4 + 2], e[mk * 4 + 3]);
      *reinterpret_cast<uint2*>(&Pw[nq * 16 + li][mk * 16 + g * 4]) = wv;
    }
    bias[nq] -= bstep;
  }

  s16x8 pb0 = *(const s16x8*)&Pw[li][g * 8];
  s16x8 pb1 = *(const s16x8*)&Pw[16 + li][g * 8];
#pragma unroll
  for (int mf = 0; mf < 8; ++mf) {
    acc[mf][0] = MFMA_BF16(vr[mf], pb0, acc[mf][0]);
    acc[mf][1] = MFMA_BF16(vr[mf], pb1, acc[mf][1]);
  }
}

__device__ __forceinline__ void attn_qtile(
    int qt, int h, int b, const u16* qbuf, const u16* kf, const u16* vf,
    u16* obuf, int l, int li, int g, float c1, float sl2, u16 (*Pw)[40]) {
  const int S = 2048;
  const int q0 = qt * 32;
  const size_t bb64 = (size_t)b * 64;

  s16x8 bq[2][4];
#pragma unroll
  for (int nq = 0; nq < 2; ++nq)
#pragma unroll
    for (int kk = 0; kk < 4; ++kk)
      bq[nq][kk] = *(const s16x8*)&qbuf[(size_t)(b * S + q0 + nq * 16 + li) * 4096
                                        + h * 128 + kk * 32 + g * 8];

  f32x4 acc[8][2];
#pragma unroll
  for (int mf = 0; mf < 8; ++mf) { acc[mf][0] = f4zero(); acc[mf][1] = f4zero(); }
  float m_[2] = {-3e38f, -3e38f};
  float lp[2] = {0.f, 0.f};

  float cjr[8];
#pragma unroll
  for (int j = 0; j < 8; ++j) cjr[j] = sl2 * (float)((j >> 2) * 16 + (j & 3));
  float bias[2];
#pragma unroll
  for (int nq = 0; nq < 2; ++nq)
    bias[nq] = sl2 * (float)(g * 4 - nq * 16 - li);
  const float bstep = sl2 * 32.f;

  s16x8 kA[8], kB[8];
  load_ktile(kA, kf, bb64 + qt, l);
  attn_tile<true>(qt, kf, vf, bb64, l, li, g, kA, kB, qt >= 1,
                  bq, acc, m_, lp, bias, c1, cjr, bstep, Pw);
  int kt = qt - 1;
  while (kt >= 1) {
    attn_tile<false>(kt, kf, vf, bb64, l, li, g, kB, kA, true,
                     bq, acc, m_, lp, bias, c1, cjr, bstep, Pw);
    attn_tile<false>(kt - 1, kf, vf, bb64, l, li, g, kA, kB, kt >= 2,
                     bq, acc, m_, lp, bias, c1, cjr, bstep, Pw);
    kt -= 2;
  }
  if (kt == 0)
    attn_tile<false>(0, kf, vf, bb64, l, li, g, kB, kA, false,
                     bq, acc, m_, lp, bias, c1, cjr, bstep, Pw);

#pragma unroll
  for (int nq = 0; nq < 2; ++nq) {
    float ls = lp[nq];
    ls += __shfl_xor(ls, 16);
    ls += __shfl_xor(ls, 32);
    const float inv = 1.f / ls;
    const size_t rowbase = (size_t)(b * S + q0 + nq * 16 + li) * 4096 + h * 128;
#pragma unroll
    for (int mf = 0; mf < 8; ++mf) {
      f32x4 v = acc[mf][nq];
      uint2 wv;
      wv.x = pkbf(v[0] * inv, v[1] * inv);
      wv.y = pkbf(v[2] * inv, v[3] * inv);
      *reinterpret_cast<uint2*>(&obuf[rowbase + mf * 16 + g * 4]) = wv;
    }
  }
}

__global__ __launch_bounds__(64, 2)
void attn_kernel(const u16* __restrict__ qbuf, const u16* __restrict__ kf,
                 const u16* __restrict__ vf, u16* __restrict__ obuf) {
  const int p = blockIdx.x, h = blockIdx.y, b = blockIdx.z;
  const int l = threadIdx.x, li = l & 15, g = l >> 4;
  const float L2E = 1.4426950408889634f;
  const float slope = exp2f(-0.25f * (float)(h + 1));
  const float c1 = 0.08838834764831845f * L2E;
  const float sl2 = slope * L2E;
  __shared__ __align__(16) u16 P[32][40];
  attn_qtile(63 - p, h, b, qbuf, kf, vf, obuf, l, li, g, c1, sl2, P);
  attn_qtile(p, h, b, qbuf, kf, vf, obuf, l, li, g, c1, sl2, P);
}

// ---------------- launch ----------------
extern "C" void kernel_launch(void* const* d_in, const int* in_sizes, int n_in,
                              void* d_out, int out_size, void* d_ws, size_t ws_size,
                              hipStream_t stream) {
  (void)in_sizes; (void)n_in; (void)out_size; (void)ws_size;
  const float* hidden = (const float*)d_in[0];
  const float* w_qkv = (const float*)d_in[1];
  const float* w_c = (const float*)d_in[2];
  float* out = (float*)d_out;
  char* ws = (char*)d_ws;

  // workspace layout (100 MB total)
  u16* hid_bf = (u16*)(ws + 0);            // 32 MB  (B*S,4096) bf16; reused as attn out
  u16* wT     = (u16*)(ws + 33554432);     // 34 MB  w_qkv^T then w_c^T (N,K) bf16
  u16* qbuf   = (u16*)(ws + 69206016);     // 32 MB  (B*S,4096) bf16
  u16* kbuf   = (u16*)(ws + 102760448);    // 1 MB   K fragment-linear
  u16* vtbuf  = (u16*)(ws + 103809024);    // 1 MB   V fragment-linear

  cvt_bf16_kernel<<<16384, 256, 0, stream>>>((const float4*)hidden, hid_bf, 4194304);
  transpose_cvt_kernel<<<dim3(136, 128), dim3(32, 8), 0, stream>>>(w_qkv, wT, 4096, 4352);
  gemm256_kernel<1><<<dim3(16, 16), 512, 0, stream>>>(hid_bf, wT, nullptr, qbuf, kbuf, vtbuf,
                                                      4352, 4096);
  attn_kernel<<<dim3(32, 32, 2), 64, 0, stream>>>(qbuf, kbuf, vtbuf, hid_bf);
  transpose_cvt_kernel<<<dim3(128, 128), dim3(32, 8), 0, stream>>>(w_c, wT, 4096, 4096);
  gemm256_kernel<0><<<dim3(16, 16), 512, 0, stream>>>(hid_bf, wT, out, nullptr, nullptr, nullptr,
                                                      4096, 4096);
}